// Round 10
// baseline (886.892 us; speedup 1.0000x reference)
//
#include <hip/hip_runtime.h>
#include <stdint.h>

#define B_ 2
#define L_ 2048
#define H_ 2048
#define NH_ 16
#define D_ 128
#define I_ 8192
#define M_ (B_*L_)

typedef unsigned short u16;
typedef __attribute__((ext_vector_type(8))) short bf16x8;
typedef __attribute__((ext_vector_type(4))) float f32x4;

__device__ __forceinline__ u16 f2bf(float f) {
  union { float f; uint32_t u; } c; c.f = f;
  return (u16)((c.u + 0x7fffu + ((c.u >> 16) & 1u)) >> 16);
}
__device__ __forceinline__ float bf2f(u16 h) {
  union { uint32_t u; float f; } c; c.u = ((uint32_t)h) << 16;
  return c.f;
}
// global -> LDS direct DMA, 16B/lane. LDS dest is wave-uniform base + lane*16.
__device__ __forceinline__ void gload16(const void* g, void* l) {
  __builtin_amdgcn_global_load_lds(
      (__attribute__((address_space(1))) void*)g,
      (__attribute__((address_space(3))) void*)l, 16, 0, 0);
}

// ---------------- fp32 -> bf16 conversion ----------------
__global__ void cvt_w(const float* __restrict__ src, u16* __restrict__ dst, int n4) {
  int i = blockIdx.x * blockDim.x + threadIdx.x;
  if (i >= n4) return;
  float4 v = ((const float4*)src)[i];
  ushort4 o;
  o.x = f2bf(v.x); o.y = f2bf(v.y); o.z = f2bf(v.z); o.w = f2bf(v.w);
  ((ushort4*)dst)[i] = o;
}

// ---------------- down-proj partial reduce: out = p0 + p1 + res ----------------
__global__ __launch_bounds__(256) void down_reduce(const u16* __restrict__ p0,
                                                   const u16* __restrict__ p1,
                                                   const float* __restrict__ res,
                                                   float* __restrict__ out, int n4) {
  int i = blockIdx.x * blockDim.x + threadIdx.x;
  if (i >= n4) return;
  ushort4 a = ((const ushort4*)p0)[i];
  ushort4 b = ((const ushort4*)p1)[i];
  float4 r = ((const float4*)res)[i];
  float4 o;
  o.x = bf2f(a.x) + bf2f(b.x) + r.x;
  o.y = bf2f(a.y) + bf2f(b.y) + r.y;
  o.z = bf2f(a.z) + bf2f(b.z) + r.z;
  o.w = bf2f(a.w) + bf2f(b.w) + r.w;
  ((float4*)out)[i] = o;
}

// ---------------- RMSNorm: one block per row ----------------
__global__ __launch_bounds__(256) void rmsnorm_k(const float* __restrict__ x,
                                                 const float* __restrict__ w,
                                                 u16* __restrict__ out) {
  int row = blockIdx.x;
  int t = threadIdx.x;
  const float4* xr = (const float4*)(x + (size_t)row * H_);
  float4 a = xr[t * 2], b = xr[t * 2 + 1];
  float s = a.x*a.x + a.y*a.y + a.z*a.z + a.w*a.w
          + b.x*b.x + b.y*b.y + b.z*b.z + b.w*b.w;
  for (int m = 1; m < 64; m <<= 1) s += __shfl_xor(s, m);
  __shared__ float sm[4];
  if ((t & 63) == 0) sm[t >> 6] = s;
  __syncthreads();
  float tot = sm[0] + sm[1] + sm[2] + sm[3];
  float rs = rsqrtf(tot / (float)H_ + 1e-6f);
  const float4* wr = (const float4*)w;
  float4 w0 = wr[t * 2], w1 = wr[t * 2 + 1];
  ushort4 o0, o1;
  o0.x = f2bf(a.x * rs * w0.x); o0.y = f2bf(a.y * rs * w0.y);
  o0.z = f2bf(a.z * rs * w0.z); o0.w = f2bf(a.w * rs * w0.w);
  o1.x = f2bf(b.x * rs * w1.x); o1.y = f2bf(b.y * rs * w1.y);
  o1.z = f2bf(b.z * rs * w1.z); o1.w = f2bf(b.w * rs * w1.w);
  ushort4* orow = (ushort4*)(out + (size_t)row * H_);
  orow[t * 2] = o0; orow[t * 2 + 1] = o1;
}

// ---------------- RoPE tables ----------------
__global__ void rope_tab(float* __restrict__ cosT, float* __restrict__ sinT,
                         const int* __restrict__ offp) {
  int i = blockIdx.x * blockDim.x + threadIdx.x;  // L_*64
  int d = i & 63, l = i >> 6;
  float inv = powf(10000.0f, -(float)d / 64.0f);
  float ang = (float)(l + *offp) * inv;
  cosT[i] = cosf(ang);
  sinT[i] = sinf(ang);
}

// ---------------- RoPE apply, in-place on (B,NH,L,D) bf16 ----------------
__global__ void rope_apply(u16* __restrict__ qk, const float* __restrict__ cosT,
                           const float* __restrict__ sinT) {
  int i = blockIdx.x * blockDim.x + threadIdx.x;  // B_*NH_*L_*64
  int d = i & 63;
  size_t row = (size_t)(i >> 6);
  int l = (int)(row & (L_ - 1));
  u16* p = qk + row * D_;
  float x1 = bf2f(p[d]), x2 = bf2f(p[d + 64]);
  float c = cosT[l * 64 + d], s = sinT[l * 64 + d];
  p[d]      = f2bf(x1 * c - x2 * s);
  p[d + 64] = f2bf(x2 * c + x1 * s);
}

// ---------------- V transpose: (B,NH,L,D) -> (B,NH,D,L) ----------------
__global__ __launch_bounds__(256) void vtrans_k(const u16* __restrict__ v,
                                                u16* __restrict__ vt) {
  __shared__ u16 tile[64][65];
  int l0 = blockIdx.x * 64, d0 = blockIdx.y * 64;
  size_t base = (size_t)blockIdx.z * L_ * D_;
  int t = threadIdx.x;
  int tr = t >> 3, tc = (t & 7) * 8;
  #pragma unroll
  for (int it = 0; it < 2; ++it) {
    int r = tr + it * 32;
    const u16* src = v + base + (size_t)(l0 + r) * D_ + d0 + tc;
    ushort4 u0 = ((const ushort4*)src)[0], u1 = ((const ushort4*)src)[1];
    tile[r][tc + 0] = u0.x; tile[r][tc + 1] = u0.y;
    tile[r][tc + 2] = u0.z; tile[r][tc + 3] = u0.w;
    tile[r][tc + 4] = u1.x; tile[r][tc + 5] = u1.y;
    tile[r][tc + 6] = u1.z; tile[r][tc + 7] = u1.w;
  }
  __syncthreads();
  #pragma unroll
  for (int it = 0; it < 2; ++it) {
    int r = tr + it * 32;
    u16* dst = vt + base + (size_t)(d0 + r) * L_ + l0 + tc;
    ushort4 o0, o1;
    o0.x = tile[tc + 0][r]; o0.y = tile[tc + 1][r];
    o0.z = tile[tc + 2][r]; o0.w = tile[tc + 3][r];
    o1.x = tile[tc + 4][r]; o1.y = tile[tc + 5][r];
    o1.z = tile[tc + 6][r]; o1.w = tile[tc + 7][r];
    ((ushort4*)dst)[0] = o0; ((ushort4*)dst)[1] = o1;
  }
}

#define EPI_QKV 0
#define EPI_SILU 1
#define EPI_MUL 2
#define EPI_ADDRES 3
#define EPI_PART 4
#define EPI_QKV3 5

// ---------------- GEMM 128x128 (m97 structure) — WO only ----------------
template <int EPI>
__global__ __launch_bounds__(256)
void gemm_bt(const u16* __restrict__ A, const u16* __restrict__ Bw,
             int M, int N, int K,
             u16* outb, float* outf, const float* __restrict__ resf) {
  __shared__ __attribute__((aligned(16))) u16 At[128 * 64];
  __shared__ __attribute__((aligned(16))) u16 Bt[128 * 64];
  int tid = threadIdx.x;
  int w = tid >> 6, lane = tid & 63;
  int r16 = lane & 15, g4 = lane >> 4;
  int wr = w >> 1, wc = w & 1;
  int m0 = blockIdx.y * 128;
  int n0 = blockIdx.x * 128;
  f32x4 acc[4][4] = {};
  const char* Ab = (const char*)A;
  const char* Bb = (const char*)Bw;
  int nk = K >> 6;
  for (int kt = 0; kt < nk; ++kt) {
    int k0 = kt << 6;
    #pragma unroll
    for (int i = 0; i < 4; ++i) {
      int uoff = i * 4096 + w * 1024;
      int lin = uoff + lane * 16;
      int row = lin >> 7;
      int colB = lin & 127;
      gload16(Ab + ((size_t)(m0 + row) * K + k0) * 2 + colB, (char*)At + uoff);
      gload16(Bb + ((size_t)(n0 + row) * K + k0) * 2 + colB, (char*)Bt + uoff);
    }
    __syncthreads();
    #pragma unroll
    for (int kk = 0; kk < 2; ++kk) {
      bf16x8 af[4], bfr[4];
      #pragma unroll
      for (int m = 0; m < 4; ++m)
        af[m] = *(const bf16x8*)&At[(wr * 64 + m * 16 + r16) * 64 + kk * 32 + g4 * 8];
      #pragma unroll
      for (int n = 0; n < 4; ++n)
        bfr[n] = *(const bf16x8*)&Bt[(wc * 64 + n * 16 + r16) * 64 + kk * 32 + g4 * 8];
      #pragma unroll
      for (int m = 0; m < 4; ++m)
        #pragma unroll
        for (int n = 0; n < 4; ++n)
          acc[m][n] = __builtin_amdgcn_mfma_f32_16x16x32_bf16(af[m], bfr[n], acc[m][n], 0, 0, 0);
    }
    __syncthreads();
  }
  #pragma unroll
  for (int m = 0; m < 4; ++m) {
    #pragma unroll
    for (int n = 0; n < 4; ++n) {
      #pragma unroll
      for (int r = 0; r < 4; ++r) {
        int row = m0 + wr * 64 + m * 16 + g4 * 4 + r;
        int col = n0 + wc * 64 + n * 16 + r16;
        float val = acc[m][n][r];
        if (EPI == EPI_QKV) {
          int b = row >> 11, l = row & 2047;
          int hh = col >> 7, d = col & 127;
          outb[((((size_t)b * NH_ + hh) * L_ + l) << 7) + d] = f2bf(val);
        } else if (EPI == EPI_SILU) {
          float sg = val / (1.0f + __expf(-val));
          outb[(size_t)row * N + col] = f2bf(sg);
        } else if (EPI == EPI_MUL) {
          float g = bf2f(outb[(size_t)row * N + col]);
          outb[(size_t)row * N + col] = f2bf(g * val);
        } else {
          outf[(size_t)row * N + col] = val + resf[(size_t)row * N + col];
        }
      }
    }
  }
}

// ---------------- GEMM 256x256 8-wave, deep-pipelined (T2+T3+T4+T5) ----------
// 512 thr = 8 waves; BK=64; LDS 128KB dbuf; column-major wg->(m,n) (r9: FETCH
// 303->180MB). m218-style counted vmcnt: 3 half-tiles permanently in flight,
// vmcnt(6) ONCE per K-tile (ph3), drain vmcnt(0) only for the last 2 iters.
// Stage stream per iter: ph0:A1(t+1) ph1:A0(t+2) ph2:B0(t+2) ph3:B1(t+2).
// Per phase: {ds_read frags || stage} -> bar -> lgkmcnt(0) -> 16 MFMA -> bar.
// LDS XOR swizzle byte^=((row&7)<<4) both-sides (rule #21).
template <int EPI>
__global__ __launch_bounds__(512, 2)
void gemm256(const u16* __restrict__ A, const u16* __restrict__ Bw,
             int M, int N, int K, int nk,
             u16* __restrict__ outb, u16* __restrict__ outb2) {
  __shared__ __attribute__((aligned(16))) u16 Asm[2][2][8192];
  __shared__ __attribute__((aligned(16))) u16 Bsm[2][2][8192];
  int tid = threadIdx.x;
  int wid = tid >> 6, lane = tid & 63;
  int r16 = lane & 15, g4 = lane >> 4;
  // bijective XCD swizzle (m204)
  int nwg = gridDim.x, bid = blockIdx.x;
  int q8 = nwg >> 3, r8 = nwg & 7, xcd = bid & 7, loc = bid >> 3;
  int wgall = (xcd < r8 ? xcd * (q8 + 1) : r8 * (q8 + 1) + (xcd - r8) * q8) + loc;
  int nwg_geo = (M >> 8) * (N >> 8);
  int ks = wgall / nwg_geo;     // split-K slice (EPI_PART)
  int wg = wgall % nwg_geo;
  int MX = M >> 8;
  int m0 = (wg % MX) * 256;     // column-major: m fastest
  int n0 = (wg / MX) * 256;
  const char* Ab = (const char*)(A + (size_t)ks * nk * 64);
  const char* Bb = (const char*)(Bw + (size_t)ks * nk * 64);
  u16* ob = (EPI == EPI_PART && ks) ? outb2 : outb;

  f32x4 acc[2][2][4][2] = {};
  bf16x8 afr[4][2];      // A frags for current qm
  bf16x8 bfr[2][2][2];   // B frags [qn][nf][kk], both qn held

  // stage half sel of tile kt1: 0:A-h0 1:B-h0 2:B-h1 3:A-h1 (2 loads/wave)
  auto STAGE = [&](int kt1, int sel) {
    if (kt1 >= nk) return;
    int buf = kt1 & 1;
    int k0 = kt1 << 6;
    const char* gb; char* lb; int row0;
    if (sel == 0)      { gb = Ab; row0 = m0;       lb = (char*)&Asm[buf][0][0]; }
    else if (sel == 3) { gb = Ab; row0 = m0 + 128; lb = (char*)&Asm[buf][1][0]; }
    else if (sel == 1) { gb = Bb; row0 = n0;       lb = (char*)&Bsm[buf][0][0]; }
    else               { gb = Bb; row0 = n0 + 128; lb = (char*)&Bsm[buf][1][0]; }
    #pragma unroll
    for (int j = 0; j < 2; ++j) {
      int p = j * 8192 + wid * 1024 + lane * 16;
      int r = p >> 7;
      int cb = (p & 127) ^ ((r & 7) << 4);
      gload16(gb + ((size_t)(row0 + r) * K + k0) * 2 + cb,
              lb + j * 8192 + wid * 1024);
    }
  };
  auto LDA = [&](int cur, int qm) {
    const char* Ah = (const char*)&Asm[cur][qm][0];
    #pragma unroll
    for (int mf = 0; mf < 4; ++mf) {
      int R = (wid >> 2) * 64 + mf * 16 + r16;
      int sw = (R & 7) << 4;
      afr[mf][0] = *(const bf16x8*)(Ah + R * 128 + ((g4 * 16) ^ sw));
      afr[mf][1] = *(const bf16x8*)(Ah + R * 128 + ((64 + g4 * 16) ^ sw));
    }
  };
  auto LDB = [&](int cur, int qn) {
    const char* Bh = (const char*)&Bsm[cur][qn][0];
    #pragma unroll
    for (int nf = 0; nf < 2; ++nf) {
      int R = (wid & 3) * 32 + nf * 16 + r16;
      int sw = (R & 7) << 4;
      bfr[qn][nf][0] = *(const bf16x8*)(Bh + R * 128 + ((g4 * 16) ^ sw));
      bfr[qn][nf][1] = *(const bf16x8*)(Bh + R * 128 + ((64 + g4 * 16) ^ sw));
    }
  };
  auto MFMA16 = [&](int qm, int qn) {
    __builtin_amdgcn_s_setprio(1);
    #pragma unroll
    for (int mf = 0; mf < 4; ++mf)
      #pragma unroll
      for (int nf = 0; nf < 2; ++nf)
        #pragma unroll
        for (int kk = 0; kk < 2; ++kk)
          acc[qm][qn][mf][nf] = __builtin_amdgcn_mfma_f32_16x16x32_bf16(
              afr[mf][kk], bfr[qn][nf][kk], acc[qm][qn][mf][nf], 0, 0, 0);
    __builtin_amdgcn_s_setprio(0);
  };

  // prologue: tile0 all 4 halves + tile1 {A0,B0,B1} = 14 loads/wave;
  // vmcnt(6) retires tile0 entirely (own-wave), barrier makes it mutual.
  STAGE(0, 0); STAGE(0, 1); STAGE(0, 2); STAGE(0, 3);
  STAGE(1, 0); STAGE(1, 1); STAGE(1, 2);
  asm volatile("s_waitcnt vmcnt(6)" ::: "memory");
  __builtin_amdgcn_s_barrier();

  for (int kt = 0; kt < nk; ++kt) {
    int cur = kt & 1;
    // ph0: read A(q0) 8 + B(q0) 4; stage A1(t+1)
    LDA(cur, 0); LDB(cur, 0);
    STAGE(kt + 1, 3);
    asm volatile("s_waitcnt lgkmcnt(8)" ::: "memory");
    __builtin_amdgcn_s_barrier();
    asm volatile("s_waitcnt lgkmcnt(0)" ::: "memory");
    __builtin_amdgcn_sched_barrier(0);
    MFMA16(0, 0);
    __builtin_amdgcn_s_barrier();
    // ph1: read B(q1) 4; stage A0(t+2)
    LDB(cur, 1);
    STAGE(kt + 2, 0);
    __builtin_amdgcn_s_barrier();
    asm volatile("s_waitcnt lgkmcnt(0)" ::: "memory");
    __builtin_amdgcn_sched_barrier(0);
    MFMA16(0, 1);
    __builtin_amdgcn_s_barrier();
    // ph2: read A(q1) 8; stage B0(t+2)
    LDA(cur, 1);
    STAGE(kt + 2, 1);
    __builtin_amdgcn_s_barrier();
    asm volatile("s_waitcnt lgkmcnt(0)" ::: "memory");
    __builtin_amdgcn_sched_barrier(0);
    MFMA16(1, 1);
    __builtin_amdgcn_s_barrier();
    // ph3: no ds_reads; stage B1(t+2); counted vmcnt once per K-tile.
    // Steady state: 8 outstanding -> vmcnt(6) retires A1(t+1) only.
    // Last 2 iters: prefetches skipped -> must drain to 0.
    STAGE(kt + 2, 2);
    if (kt + 3 <= nk) {
      asm volatile("s_waitcnt vmcnt(6)" ::: "memory");
    } else {
      asm volatile("s_waitcnt vmcnt(0)" ::: "memory");
    }
    __builtin_amdgcn_s_barrier();
    __builtin_amdgcn_sched_barrier(0);
    MFMA16(1, 0);
    __builtin_amdgcn_s_barrier();
  }
  // epilogue
  #pragma unroll
  for (int qm = 0; qm < 2; ++qm)
    #pragma unroll
    for (int qn = 0; qn < 2; ++qn)
      #pragma unroll
      for (int mf = 0; mf < 4; ++mf)
        #pragma unroll
        for (int nf = 0; nf < 2; ++nf)
          #pragma unroll
          for (int rr = 0; rr < 4; ++rr) {
            int row = m0 + qm * 128 + (wid >> 2) * 64 + mf * 16 + g4 * 4 + rr;
            int col = n0 + qn * 128 + (wid & 3) * 32 + nf * 16 + r16;
            float val = acc[qm][qn][mf][nf][rr];
            if (EPI == EPI_SILU) {
              ob[(size_t)row * N + col] = f2bf(val / (1.0f + __expf(-val)));
            } else if (EPI == EPI_MUL) {
              float g = bf2f(ob[(size_t)row * N + col]);
              ob[(size_t)row * N + col] = f2bf(g * val);
            } else if (EPI == EPI_PART) {
              ob[(size_t)row * N + col] = f2bf(val);
            } else if (EPI == EPI_QKV3) {
              int which = col >> 11, within = col & 2047;
              int hh = within >> 7, d = within & 127;
              int bb = row >> 11, l = row & 2047;
              ob[(size_t)which * M_ * H_ +
                 ((((size_t)bb * NH_ + hh) * L_ + l) << 7) + d] = f2bf(val);
            }
          }
}

// ---------------- Flash attention (causal), XOR-swizzled LDS ----------------
__global__ __launch_bounds__(256)
void flash_attn(const u16* __restrict__ q, const u16* __restrict__ k,
                const u16* __restrict__ vt, u16* __restrict__ out) {
  __shared__ __attribute__((aligned(16))) u16 Kt[64 * 128];
  __shared__ __attribute__((aligned(16))) u16 Vt[128 * 64];
  __shared__ __attribute__((aligned(16))) u16 Pl[4][16 * 64];
  int tid = threadIdx.x, w = tid >> 6, lane = tid & 63;
  int r16 = lane & 15, g4 = lane >> 4;
  int b = blockIdx.z, h = blockIdx.y;
  int qt = gridDim.x - 1 - blockIdx.x;
  int q0 = qt * 64;
  size_t bh = (size_t)b * NH_ + h;
  const char* qb = (const char*)(q + bh * L_ * D_);
  const char* kb = (const char*)(k + bh * L_ * D_);
  const char* vb = (const char*)(vt + bh * D_ * L_);
  int qrow = q0 + w * 16 + r16;
  bf16x8 qf[4];
  #pragma unroll
  for (int c = 0; c < 4; ++c)
    qf[c] = *(const bf16x8*)(qb + ((size_t)qrow * 128 + c * 32 + g4 * 8) * 2);
  f32x4 oacc[8] = {};
  float mrow[4], lsum[4];
  #pragma unroll
  for (int r = 0; r < 4; ++r) { mrow[r] = -3.0e38f; lsum[r] = 0.f; }
  int myq = q0 + w * 16 + g4 * 4;
  int ntiles = qt + 1;
  int rsw = (r16 & 7) << 4;
  const float sc = 0.08838834764831845f;
  for (int t = 0; t < ntiles; ++t) {
    int kv0 = t * 64;
    #pragma unroll
    for (int i = 0; i < 4; ++i) {
      int uoff = i * 4096 + w * 1024;
      int lin = uoff + lane * 16;
      int krow = lin >> 8;
      int kcol = (lin & 255) ^ ((krow & 7) << 4);
      gload16(kb + (size_t)(kv0 + krow) * 256 + kcol, (char*)Kt + uoff);
      int vrow = lin >> 7;
      int vcol = (lin & 127) ^ ((vrow & 7) << 4);
      gload16(vb + (size_t)vrow * (L_ * 2) + kv0 * 2 + vcol, (char*)Vt + uoff);
    }
    __syncthreads();
    f32x4 s[4] = {};
    __builtin_amdgcn_s_setprio(1);
    #pragma unroll
    for (int c = 0; c < 4; ++c) {
      #pragma unroll
      for (int n = 0; n < 4; ++n) {
        const char* kp = (const char*)Kt + (n * 16 + r16) * 256
                       + ((c * 64 + g4 * 16) ^ rsw);
        bf16x8 kf = *(const bf16x8*)kp;
        s[n] = __builtin_amdgcn_mfma_f32_16x16x32_bf16(qf[c], kf, s[n], 0, 0, 0);
      }
    }
    __builtin_amdgcn_s_setprio(0);
    #pragma unroll
    for (int r = 0; r < 4; ++r) {
      float rm = -3.0e38f;
      #pragma unroll
      for (int n = 0; n < 4; ++n) {
        float v = s[n][r] * sc;
        int kvi = kv0 + n * 16 + r16;
        if (kvi > myq + r) v = -3.0e38f;
        s[n][r] = v;
        rm = fmaxf(rm, v);
      }
      rm = fmaxf(rm, __shfl_xor(rm, 1));
      rm = fmaxf(rm, __shfl_xor(rm, 2));
      rm = fmaxf(rm, __shfl_xor(rm, 4));
      rm = fmaxf(rm, __shfl_xor(rm, 8));
      float mnew = fmaxf(mrow[r], rm);
      float alpha = __expf(mrow[r] - mnew);
      mrow[r] = mnew;
      lsum[r] *= alpha;
      #pragma unroll
      for (int nf = 0; nf < 8; ++nf) oacc[nf][r] *= alpha;
      int prow = g4 * 4 + r;
      int psw = (prow & 7) << 3;
      #pragma unroll
      for (int n = 0; n < 4; ++n) {
        float pv = __expf(s[n][r] - mnew);
        lsum[r] += pv;
        Pl[w][prow * 64 + ((n * 16 + r16) ^ psw)] = f2bf(pv);
      }
    }
    asm volatile("s_waitcnt lgkmcnt(0)" ::: "memory");
    __builtin_amdgcn_sched_barrier(0);
    __builtin_amdgcn_s_setprio(1);
    #pragma unroll
    for (int kc = 0; kc < 2; ++kc) {
      const char* pp = (const char*)&Pl[w][0] + r16 * 128
                     + ((kc * 64 + g4 * 16) ^ rsw);
      bf16x8 pf = *(const bf16x8*)pp;
      #pragma unroll
      for (int nf = 0; nf < 8; ++nf) {
        const char* vp = (const char*)Vt + (nf * 16 + r16) * 128
                       + ((kc * 64 + g4 * 16) ^ rsw);
        bf16x8 vf = *(const bf16x8*)vp;
        oacc[nf] = __builtin_amdgcn_mfma_f32_16x16x32_bf16(pf, vf, oacc[nf], 0, 0, 0);
      }
    }
    __builtin_amdgcn_s_setprio(0);
    __syncthreads();
  }
  #pragma unroll
  for (int r = 0; r < 4; ++r) {
    float l = lsum[r];
    l += __shfl_xor(l, 1); l += __shfl_xor(l, 2);
    l += __shfl_xor(l, 4); l += __shfl_xor(l, 8);
    float inv = 1.0f / l;
    size_t orow = ((size_t)b * L_ + (myq + r)) * H_ + h * D_;
    #pragma unroll
    for (int nf = 0; nf < 8; ++nf)
      out[orow + nf * 16 + r16] = f2bf(oacc[nf][r] * inv);
  }
}

// ---------------- host orchestration ----------------
extern "C" void kernel_launch(void* const* d_in, const int* in_sizes, int n_in,
                              void* d_out, int out_size, void* d_ws, size_t ws_size,
                              hipStream_t stream) {
  (void)in_sizes; (void)n_in; (void)out_size; (void)ws_size;
  const float* x    = (const float*)d_in[0];
  const float* ln1w = (const float*)d_in[1];
  const float* ln2w = (const float*)d_in[2];
  const float* wq   = (const float*)d_in[3];
  const float* wk   = (const float*)d_in[4];
  const float* wv   = (const float*)d_in[5];
  const float* wo   = (const float*)d_in[6];
  const float* wg   = (const float*)d_in[7];
  const float* wu   = (const float*)d_in[8];
  const float* wd   = (const float*)d_in[9];
  const int*   offp = (const int*)d_in[11];
  float* out = (float*)d_out;

  char* p = (char*)d_ws;
  auto alloc = [&](size_t bytes) {
    char* r = p;
    p += (bytes + 255) & ~(size_t)255;
    return r;
  };
  const size_t HH = (size_t)H_ * H_, IH = (size_t)I_ * H_;
  u16* wbuf = (u16*)alloc(IH * 2);                  // 32 MB, reused
  u16* h1   = (u16*)alloc((size_t)M_ * H_ * 2);     // 16 MB (h2; down partial 0)
  u16* qb   = (u16*)alloc((size_t)M_ * H_ * 2);     // 16 MB (qb..vtb reused as gateb)
  u16* kb   = (u16*)alloc((size_t)M_ * H_ * 2);     // 16 MB
  u16* vb   = (u16*)alloc((size_t)M_ * H_ * 2);     // 16 MB
  u16* vtb  = (u16*)alloc((size_t)M_ * H_ * 2);     // 16 MB
  u16* attn = (u16*)alloc((size_t)M_ * H_ * 2);     // 16 MB (down partial 1)
  float* x2 = (float*)alloc((size_t)M_ * H_ * 4);   // 32 MB
  float* cosT = (float*)alloc((size_t)L_ * 64 * 4);
  float* sinT = (float*)alloc((size_t)L_ * 64 * 4);
  (void)kb; (void)vb;
  u16* h2    = h1;   // h1 dead after QKV GEMM
  u16* gateb = qb;   // qb..vtb region (64 MB) dead after flash_attn

  const int nHH4 = (int)(HH / 4), nIH4 = (int)(IH / 4);

  rmsnorm_k<<<M_, 256, 0, stream>>>(x, ln1w, h1);
  rope_tab<<<(L_ * 64) / 256, 256, 0, stream>>>(cosT, sinT, offp);

  // fused QKV: wq/wk/wv stacked -> one N=6144 GEMM, scatter epilogue
  cvt_w<<<nHH4 / 256, 256, 0, stream>>>(wq, wbuf, nHH4);
  cvt_w<<<nHH4 / 256, 256, 0, stream>>>(wk, wbuf + HH, nHH4);
  cvt_w<<<nHH4 / 256, 256, 0, stream>>>(wv, wbuf + 2 * HH, nHH4);
  int nwg_qkv = (M_ / 256) * (3 * H_ / 256);   // 16*24 = 384
  gemm256<EPI_QKV3><<<nwg_qkv, 512, 0, stream>>>(h1, wbuf, M_, 3 * H_, H_,
                                                 H_ / 64, qb, nullptr);

  int nrope = B_ * NH_ * L_ * 64;
  rope_apply<<<nrope / 256, 256, 0, stream>>>(qb, cosT, sinT);
  rope_apply<<<nrope / 256, 256, 0, stream>>>(qb + (size_t)M_ * H_, cosT, sinT);
  vtrans_k<<<dim3(L_ / 64, D_ / 64, B_ * NH_), 256, 0, stream>>>(
      qb + 2 * (size_t)M_ * H_, vtb);

  flash_attn<<<dim3(L_ / 64, NH_, B_), 256, 0, stream>>>(
      qb, qb + (size_t)M_ * H_, vtb, attn);

  dim3 g1(H_ / 128, M_ / 128);
  cvt_w<<<nHH4 / 256, 256, 0, stream>>>(wo, wbuf, nHH4);
  gemm_bt<EPI_ADDRES><<<g1, 256, 0, stream>>>(attn, wbuf, M_, H_, H_, nullptr, x2, x);
  rmsnorm_k<<<M_, 256, 0, stream>>>(x2, ln2w, h2);

  // MLP gate/up on the 256^2 kernel (512 blocks each)
  int nwg256 = (M_ / 256) * (I_ / 256);
  cvt_w<<<nIH4 / 256, 256, 0, stream>>>(wg, wbuf, nIH4);
  gemm256<EPI_SILU><<<nwg256, 512, 0, stream>>>(h2, wbuf, M_, I_, H_,
                                                H_ / 64, gateb, nullptr);
  cvt_w<<<nIH4 / 256, 256, 0, stream>>>(wu, wbuf, nIH4);
  gemm256<EPI_MUL><<<nwg256, 512, 0, stream>>>(h2, wbuf, M_, I_, H_,
                                               H_ / 64, gateb, nullptr);

  // down-proj: split-K=2 (grid 256 = 1 block/CU), bf16 partials, reduce
  cvt_w<<<nIH4 / 256, 256, 0, stream>>>(wd, wbuf, nIH4);
  int nwg_dn = 2 * (M_ / 256) * (H_ / 256);    // 2*16*8 = 256
  gemm256<EPI_PART><<<nwg_dn, 512, 0, stream>>>(gateb, wbuf, M_, H_, I_,
                                                I_ / 128, h1, attn);
  down_reduce<<<(M_ * H_ / 4) / 256, 256, 0, stream>>>(h1, attn, x2, out,
                                                       M_ * H_ / 4);
}

// Round 11
// 853.172 us; speedup vs baseline: 1.0395x; 1.0395x over previous
//
#include <hip/hip_runtime.h>
#include <stdint.h>

#define B_ 2
#define L_ 2048
#define H_ 2048
#define NH_ 16
#define D_ 128
#define I_ 8192
#define M_ (B_*L_)

typedef unsigned short u16;
typedef __attribute__((ext_vector_type(8))) short bf16x8;
typedef __attribute__((ext_vector_type(4))) float f32x4;

__device__ __forceinline__ u16 f2bf(float f) {
  union { float f; uint32_t u; } c; c.f = f;
  return (u16)((c.u + 0x7fffu + ((c.u >> 16) & 1u)) >> 16);
}
__device__ __forceinline__ float bf2f(u16 h) {
  union { uint32_t u; float f; } c; c.u = ((uint32_t)h) << 16;
  return c.f;
}
// global -> LDS direct DMA, 16B/lane. LDS dest is wave-uniform base + lane*16.
__device__ __forceinline__ void gload16(const void* g, void* l) {
  __builtin_amdgcn_global_load_lds(
      (__attribute__((address_space(1))) void*)g,
      (__attribute__((address_space(3))) void*)l, 16, 0, 0);
}

// ---------------- fp32 -> bf16 conversion ----------------
__global__ void cvt_w(const float* __restrict__ src, u16* __restrict__ dst, int n4) {
  int i = blockIdx.x * blockDim.x + threadIdx.x;
  if (i >= n4) return;
  float4 v = ((const float4*)src)[i];
  ushort4 o;
  o.x = f2bf(v.x); o.y = f2bf(v.y); o.z = f2bf(v.z); o.w = f2bf(v.w);
  ((ushort4*)dst)[i] = o;
}

// ---------------- split-K partial reduce: out = p0 + p1 + res (fp32) --------
__global__ __launch_bounds__(256) void down_reduce(const u16* __restrict__ p0,
                                                   const u16* __restrict__ p1,
                                                   const float* __restrict__ res,
                                                   float* __restrict__ out, int n4) {
  int i = blockIdx.x * blockDim.x + threadIdx.x;
  if (i >= n4) return;
  ushort4 a = ((const ushort4*)p0)[i];
  ushort4 b = ((const ushort4*)p1)[i];
  float4 r = ((const float4*)res)[i];
  float4 o;
  o.x = bf2f(a.x) + bf2f(b.x) + r.x;
  o.y = bf2f(a.y) + bf2f(b.y) + r.y;
  o.z = bf2f(a.z) + bf2f(b.z) + r.z;
  o.w = bf2f(a.w) + bf2f(b.w) + r.w;
  ((float4*)out)[i] = o;
}

// ---------------- RMSNorm: one block per row ----------------
__global__ __launch_bounds__(256) void rmsnorm_k(const float* __restrict__ x,
                                                 const float* __restrict__ w,
                                                 u16* __restrict__ out) {
  int row = blockIdx.x;
  int t = threadIdx.x;
  const float4* xr = (const float4*)(x + (size_t)row * H_);
  float4 a = xr[t * 2], b = xr[t * 2 + 1];
  float s = a.x*a.x + a.y*a.y + a.z*a.z + a.w*a.w
          + b.x*b.x + b.y*b.y + b.z*b.z + b.w*b.w;
  for (int m = 1; m < 64; m <<= 1) s += __shfl_xor(s, m);
  __shared__ float sm[4];
  if ((t & 63) == 0) sm[t >> 6] = s;
  __syncthreads();
  float tot = sm[0] + sm[1] + sm[2] + sm[3];
  float rs = rsqrtf(tot / (float)H_ + 1e-6f);
  const float4* wr = (const float4*)w;
  float4 w0 = wr[t * 2], w1 = wr[t * 2 + 1];
  ushort4 o0, o1;
  o0.x = f2bf(a.x * rs * w0.x); o0.y = f2bf(a.y * rs * w0.y);
  o0.z = f2bf(a.z * rs * w0.z); o0.w = f2bf(a.w * rs * w0.w);
  o1.x = f2bf(b.x * rs * w1.x); o1.y = f2bf(b.y * rs * w1.y);
  o1.z = f2bf(b.z * rs * w1.z); o1.w = f2bf(b.w * rs * w1.w);
  ushort4* orow = (ushort4*)(out + (size_t)row * H_);
  orow[t * 2] = o0; orow[t * 2 + 1] = o1;
}

// ---------------- RoPE tables ----------------
__global__ void rope_tab(float* __restrict__ cosT, float* __restrict__ sinT,
                         const int* __restrict__ offp) {
  int i = blockIdx.x * blockDim.x + threadIdx.x;  // L_*64
  int d = i & 63, l = i >> 6;
  float inv = powf(10000.0f, -(float)d / 64.0f);
  float ang = (float)(l + *offp) * inv;
  cosT[i] = cosf(ang);
  sinT[i] = sinf(ang);
}

// ---------------- RoPE apply, in-place on (B,NH,L,D) bf16 ----------------
__global__ void rope_apply(u16* __restrict__ qk, const float* __restrict__ cosT,
                           const float* __restrict__ sinT) {
  int i = blockIdx.x * blockDim.x + threadIdx.x;  // B_*NH_*L_*64
  int d = i & 63;
  size_t row = (size_t)(i >> 6);
  int l = (int)(row & (L_ - 1));
  u16* p = qk + row * D_;
  float x1 = bf2f(p[d]), x2 = bf2f(p[d + 64]);
  float c = cosT[l * 64 + d], s = sinT[l * 64 + d];
  p[d]      = f2bf(x1 * c - x2 * s);
  p[d + 64] = f2bf(x2 * c + x1 * s);
}

// ---------------- V transpose: (B,NH,L,D) -> (B,NH,D,L) ----------------
__global__ __launch_bounds__(256) void vtrans_k(const u16* __restrict__ v,
                                                u16* __restrict__ vt) {
  __shared__ u16 tile[64][65];
  int l0 = blockIdx.x * 64, d0 = blockIdx.y * 64;
  size_t base = (size_t)blockIdx.z * L_ * D_;
  int t = threadIdx.x;
  int tr = t >> 3, tc = (t & 7) * 8;
  #pragma unroll
  for (int it = 0; it < 2; ++it) {
    int r = tr + it * 32;
    const u16* src = v + base + (size_t)(l0 + r) * D_ + d0 + tc;
    ushort4 u0 = ((const ushort4*)src)[0], u1 = ((const ushort4*)src)[1];
    tile[r][tc + 0] = u0.x; tile[r][tc + 1] = u0.y;
    tile[r][tc + 2] = u0.z; tile[r][tc + 3] = u0.w;
    tile[r][tc + 4] = u1.x; tile[r][tc + 5] = u1.y;
    tile[r][tc + 6] = u1.z; tile[r][tc + 7] = u1.w;
  }
  __syncthreads();
  #pragma unroll
  for (int it = 0; it < 2; ++it) {
    int r = tr + it * 32;
    u16* dst = vt + base + (size_t)(d0 + r) * L_ + l0 + tc;
    ushort4 o0, o1;
    o0.x = tile[tc + 0][r]; o0.y = tile[tc + 1][r];
    o0.z = tile[tc + 2][r]; o0.w = tile[tc + 3][r];
    o1.x = tile[tc + 4][r]; o1.y = tile[tc + 5][r];
    o1.z = tile[tc + 6][r]; o1.w = tile[tc + 7][r];
    ((ushort4*)dst)[0] = o0; ((ushort4*)dst)[1] = o1;
  }
}

#define EPI_SILU 1
#define EPI_MUL 2
#define EPI_PART 4
#define EPI_QKV3 5

// ---------------- GEMM 256x256 8-wave quadrant-phased (r9 structure) ---------
// 512 thr = 8 waves; BK=64; LDS 128KB dbuf; vmcnt(4) counted waits; LDS XOR
// swizzle both-sides (rule #21); column-major wg->(m,n) (r9: FETCH 303->180MB).
// NOTE (r6/r8/r10 post-mortem): MfmaUtil pinned at ~30% by LDS-read pipe
// (192KB frag reads per K-tile per block vs ~620cyc MFMA) — schedule variants
// are null; this is the best-measured variant. Do not re-tune the K-loop.
template <int EPI>
__global__ __launch_bounds__(512, 2)
void gemm256(const u16* __restrict__ A, const u16* __restrict__ Bw,
             int M, int N, int K, int nk,
             u16* __restrict__ outb, u16* __restrict__ outb2) {
  __shared__ __attribute__((aligned(16))) u16 Asm[2][2][8192];
  __shared__ __attribute__((aligned(16))) u16 Bsm[2][2][8192];
  int tid = threadIdx.x;
  int wid = tid >> 6, lane = tid & 63;
  int r16 = lane & 15, g4 = lane >> 4;
  // bijective XCD swizzle (m204)
  int nwg = gridDim.x, bid = blockIdx.x;
  int q8 = nwg >> 3, r8 = nwg & 7, xcd = bid & 7, loc = bid >> 3;
  int wgall = (xcd < r8 ? xcd * (q8 + 1) : r8 * (q8 + 1) + (xcd - r8) * q8) + loc;
  int nwg_geo = (M >> 8) * (N >> 8);
  int ks = wgall / nwg_geo;     // split-K slice (EPI_PART)
  int wg = wgall % nwg_geo;
  int MX = M >> 8;
  int m0 = (wg % MX) * 256;     // column-major: m fastest
  int n0 = (wg / MX) * 256;
  const char* Ab = (const char*)(A + (size_t)ks * nk * 64);
  const char* Bb = (const char*)(Bw + (size_t)ks * nk * 64);
  u16* ob = (EPI == EPI_PART && ks) ? outb2 : outb;

  f32x4 acc[2][2][4][2] = {};
  bf16x8 afr[4][2];      // A frags for current qm
  bf16x8 bfr[2][2][2];   // B frags [qn][nf][kk], both qn held

  // stage half sel of tile kt1: 0:A-h0 1:B-h0 2:B-h1 3:A-h1
  auto STAGE = [&](int kt1, int sel) {
    if (kt1 >= nk) return;
    int buf = kt1 & 1;
    int k0 = kt1 << 6;
    const char* gb; char* lb; int row0;
    if (sel == 0)      { gb = Ab; row0 = m0;       lb = (char*)&Asm[buf][0][0]; }
    else if (sel == 3) { gb = Ab; row0 = m0 + 128; lb = (char*)&Asm[buf][1][0]; }
    else if (sel == 1) { gb = Bb; row0 = n0;       lb = (char*)&Bsm[buf][0][0]; }
    else               { gb = Bb; row0 = n0 + 128; lb = (char*)&Bsm[buf][1][0]; }
    #pragma unroll
    for (int j = 0; j < 2; ++j) {
      int p = j * 8192 + wid * 1024 + lane * 16;
      int r = p >> 7;
      int cb = (p & 127) ^ ((r & 7) << 4);
      gload16(gb + ((size_t)(row0 + r) * K + k0) * 2 + cb,
              lb + j * 8192 + wid * 1024);
    }
  };

  // prologue: tile 0, order A0,B0,B1,A1 (8 loads in flight)
  STAGE(0, 0); STAGE(0, 1); STAGE(0, 2); STAGE(0, 3);

  const int QM[4] = {0, 0, 1, 1};
  const int QN[4] = {0, 1, 1, 0};

  for (int kt = 0; kt < nk; ++kt) {
    int cur = kt & 1;
    #pragma unroll
    for (int ph = 0; ph < 4; ++ph) {
      if (ph < 3) {
        __builtin_amdgcn_sched_barrier(0);
        asm volatile("s_waitcnt vmcnt(4)" ::: "memory");
      }
      __builtin_amdgcn_s_barrier();
      __builtin_amdgcn_sched_barrier(0);
      const int qm = QM[ph], qn = QN[ph];
      if (ph == 0 || ph == 2) {            // (re)load A frags for this qm
        const char* Ah = (const char*)&Asm[cur][qm][0];
        #pragma unroll
        for (int mf = 0; mf < 4; ++mf) {
          int R = (wid >> 2) * 64 + mf * 16 + r16;
          int sw = (R & 7) << 4;
          afr[mf][0] = *(const bf16x8*)(Ah + R * 128 + ((g4 * 16) ^ sw));
          afr[mf][1] = *(const bf16x8*)(Ah + R * 128 + ((64 + g4 * 16) ^ sw));
        }
      }
      if (ph == 0 || ph == 1) {            // load B frags for this qn
        const char* Bh = (const char*)&Bsm[cur][qn][0];
        #pragma unroll
        for (int nf = 0; nf < 2; ++nf) {
          int R = (wid & 3) * 32 + nf * 16 + r16;
          int sw = (R & 7) << 4;
          bfr[qn][nf][0] = *(const bf16x8*)(Bh + R * 128 + ((g4 * 16) ^ sw));
          bfr[qn][nf][1] = *(const bf16x8*)(Bh + R * 128 + ((64 + g4 * 16) ^ sw));
        }
      }
      STAGE(kt + 1, ph);                    // next tile, one half per phase
      __builtin_amdgcn_s_setprio(1);
      #pragma unroll
      for (int mf = 0; mf < 4; ++mf)
        #pragma unroll
        for (int nf = 0; nf < 2; ++nf)
          #pragma unroll
          for (int kk = 0; kk < 2; ++kk)
            acc[qm][qn][mf][nf] = __builtin_amdgcn_mfma_f32_16x16x32_bf16(
                afr[mf][kk], bfr[qn][nf][kk], acc[qm][qn][mf][nf], 0, 0, 0);
      __builtin_amdgcn_s_setprio(0);
    }
  }
  // epilogue
  #pragma unroll
  for (int qm = 0; qm < 2; ++qm)
    #pragma unroll
    for (int qn = 0; qn < 2; ++qn)
      #pragma unroll
      for (int mf = 0; mf < 4; ++mf)
        #pragma unroll
        for (int nf = 0; nf < 2; ++nf)
          #pragma unroll
          for (int rr = 0; rr < 4; ++rr) {
            int row = m0 + qm * 128 + (wid >> 2) * 64 + mf * 16 + g4 * 4 + rr;
            int col = n0 + qn * 128 + (wid & 3) * 32 + nf * 16 + r16;
            float val = acc[qm][qn][mf][nf][rr];
            if (EPI == EPI_SILU) {
              ob[(size_t)row * N + col] = f2bf(val / (1.0f + __expf(-val)));
            } else if (EPI == EPI_MUL) {
              float g = bf2f(ob[(size_t)row * N + col]);
              ob[(size_t)row * N + col] = f2bf(g * val);
            } else if (EPI == EPI_PART) {
              ob[(size_t)row * N + col] = f2bf(val);
            } else if (EPI == EPI_QKV3) {
              int which = col >> 11, within = col & 2047;
              int hh = within >> 7, d = within & 127;
              int bb = row >> 11, l = row & 2047;
              ob[(size_t)which * M_ * H_ +
                 ((((size_t)bb * NH_ + hh) * L_ + l) << 7) + d] = f2bf(val);
            }
          }
}

// ---------------- Flash attention (causal), XOR-swizzled LDS, K/V dbuf ------
// 2-phase pipeline (T3 minimum recipe): STAGE(t+1,buf^1) issued BEFORE the
// compute of tile t; __syncthreads at iter end drains vmcnt AFTER ~600cyc of
// MFMA/softmax (was: drain before compute = full HBM latency exposed).
// Race check: end-of-iter barrier guarantees buf^1 reads (iter t-1) complete
// before iter t re-stages it. LDS 72KB -> 2 blocks/CU.
__global__ __launch_bounds__(256)
void flash_attn(const u16* __restrict__ q, const u16* __restrict__ k,
                const u16* __restrict__ vt, u16* __restrict__ out) {
  __shared__ __attribute__((aligned(16))) u16 Kt[2][64 * 128];
  __shared__ __attribute__((aligned(16))) u16 Vt[2][128 * 64];
  __shared__ __attribute__((aligned(16))) u16 Pl[4][16 * 64];
  int tid = threadIdx.x, w = tid >> 6, lane = tid & 63;
  int r16 = lane & 15, g4 = lane >> 4;
  int b = blockIdx.z, h = blockIdx.y;
  int qt = gridDim.x - 1 - blockIdx.x;   // longest blocks dispatch first
  int q0 = qt * 64;
  size_t bh = (size_t)b * NH_ + h;
  const char* qb = (const char*)(q + bh * L_ * D_);
  const char* kb = (const char*)(k + bh * L_ * D_);
  const char* vb = (const char*)(vt + bh * D_ * L_);
  int qrow = q0 + w * 16 + r16;
  bf16x8 qf[4];
  #pragma unroll
  for (int c = 0; c < 4; ++c)
    qf[c] = *(const bf16x8*)(qb + ((size_t)qrow * 128 + c * 32 + g4 * 8) * 2);
  f32x4 oacc[8] = {};
  float mrow[4], lsum[4];
  #pragma unroll
  for (int r = 0; r < 4; ++r) { mrow[r] = -3.0e38f; lsum[r] = 0.f; }
  int myq = q0 + w * 16 + g4 * 4;
  int ntiles = qt + 1;
  int rsw = (r16 & 7) << 4;
  const float sc = 0.08838834764831845f;

  auto STAGEKV = [&](int t, int buf) {
    if (t >= ntiles) return;
    int kv0 = t * 64;
    #pragma unroll
    for (int i = 0; i < 4; ++i) {
      int uoff = i * 4096 + w * 1024;
      int lin = uoff + lane * 16;
      int krow = lin >> 8;
      int kcol = (lin & 255) ^ ((krow & 7) << 4);
      gload16(kb + (size_t)(kv0 + krow) * 256 + kcol,
              (char*)&Kt[buf][0] + uoff);
      int vrow = lin >> 7;
      int vcol = (lin & 127) ^ ((vrow & 7) << 4);
      gload16(vb + (size_t)vrow * (L_ * 2) + kv0 * 2 + vcol,
              (char*)&Vt[buf][0] + uoff);
    }
  };

  STAGEKV(0, 0);
  __syncthreads();   // implicit vmcnt(0) drain before first compute

  for (int t = 0; t < ntiles; ++t) {
    int buf = t & 1;
    int kv0 = t * 64;
    STAGEKV(t + 1, buf ^ 1);   // prefetch next tile; lands during compute
    const char* Kb = (const char*)&Kt[buf][0];
    const char* Vb = (const char*)&Vt[buf][0];
    // S = Q K^T
    f32x4 s[4] = {};
    __builtin_amdgcn_s_setprio(1);
    #pragma unroll
    for (int c = 0; c < 4; ++c) {
      #pragma unroll
      for (int n = 0; n < 4; ++n) {
        bf16x8 kf = *(const bf16x8*)(Kb + (n * 16 + r16) * 256
                                     + ((c * 64 + g4 * 16) ^ rsw));
        s[n] = __builtin_amdgcn_mfma_f32_16x16x32_bf16(qf[c], kf, s[n], 0, 0, 0);
      }
    }
    __builtin_amdgcn_s_setprio(0);
    // scale + causal mask + online softmax
    #pragma unroll
    for (int r = 0; r < 4; ++r) {
      float rm = -3.0e38f;
      #pragma unroll
      for (int n = 0; n < 4; ++n) {
        float v = s[n][r] * sc;
        int kvi = kv0 + n * 16 + r16;
        if (kvi > myq + r) v = -3.0e38f;
        s[n][r] = v;
        rm = fmaxf(rm, v);
      }
      rm = fmaxf(rm, __shfl_xor(rm, 1));
      rm = fmaxf(rm, __shfl_xor(rm, 2));
      rm = fmaxf(rm, __shfl_xor(rm, 4));
      rm = fmaxf(rm, __shfl_xor(rm, 8));
      float mnew = fmaxf(mrow[r], rm);
      float alpha = __expf(mrow[r] - mnew);
      mrow[r] = mnew;
      lsum[r] *= alpha;
      #pragma unroll
      for (int nf = 0; nf < 8; ++nf) oacc[nf][r] *= alpha;
      int prow = g4 * 4 + r;
      int psw = (prow & 7) << 3;
      #pragma unroll
      for (int n = 0; n < 4; ++n) {
        float pv = __expf(s[n][r] - mnew);
        lsum[r] += pv;
        Pl[w][prow * 64 + ((n * 16 + r16) ^ psw)] = f2bf(pv);
      }
    }
    // wave-internal LDS visibility fence (guide rule #18)
    asm volatile("s_waitcnt lgkmcnt(0)" ::: "memory");
    __builtin_amdgcn_sched_barrier(0);
    // O += P V
    __builtin_amdgcn_s_setprio(1);
    #pragma unroll
    for (int kc = 0; kc < 2; ++kc) {
      bf16x8 pf = *(const bf16x8*)((const char*)&Pl[w][0] + r16 * 128
                                   + ((kc * 64 + g4 * 16) ^ rsw));
      #pragma unroll
      for (int nf = 0; nf < 8; ++nf) {
        bf16x8 vf = *(const bf16x8*)(Vb + (nf * 16 + r16) * 128
                                     + ((kc * 64 + g4 * 16) ^ rsw));
        oacc[nf] = __builtin_amdgcn_mfma_f32_16x16x32_bf16(pf, vf, oacc[nf], 0, 0, 0);
      }
    }
    __builtin_amdgcn_s_setprio(0);
    __syncthreads();   // drains prefetch (vmcnt(0)) + publishes buf^1
  }
  #pragma unroll
  for (int r = 0; r < 4; ++r) {
    float l = lsum[r];
    l += __shfl_xor(l, 1); l += __shfl_xor(l, 2);
    l += __shfl_xor(l, 4); l += __shfl_xor(l, 8);
    float inv = 1.0f / l;
    size_t orow = ((size_t)b * L_ + (myq + r)) * H_ + h * D_;
    #pragma unroll
    for (int nf = 0; nf < 8; ++nf)
      out[orow + nf * 16 + r16] = f2bf(oacc[nf][r] * inv);
  }
}

// ---------------- host orchestration ----------------
extern "C" void kernel_launch(void* const* d_in, const int* in_sizes, int n_in,
                              void* d_out, int out_size, void* d_ws, size_t ws_size,
                              hipStream_t stream) {
  (void)in_sizes; (void)n_in; (void)out_size; (void)ws_size;
  const float* x    = (const float*)d_in[0];
  const float* ln1w = (const float*)d_in[1];
  const float* ln2w = (const float*)d_in[2];
  const float* wq   = (const float*)d_in[3];
  const float* wk   = (const float*)d_in[4];
  const float* wv   = (const float*)d_in[5];
  const float* wo   = (const float*)d_in[6];
  const float* wg   = (const float*)d_in[7];
  const float* wu   = (const float*)d_in[8];
  const float* wd   = (const float*)d_in[9];
  const int*   offp = (const int*)d_in[11];
  float* out = (float*)d_out;

  char* p = (char*)d_ws;
  auto alloc = [&](size_t bytes) {
    char* r = p;
    p += (bytes + 255) & ~(size_t)255;
    return r;
  };
  const size_t HH = (size_t)H_ * H_, IH = (size_t)I_ * H_;
  u16* wbuf = (u16*)alloc(IH * 2);                  // 32 MB, reused
  u16* h1   = (u16*)alloc((size_t)M_ * H_ * 2);     // 16 MB (h2; down partial 0)
  u16* qb   = (u16*)alloc((size_t)M_ * H_ * 2);     // 16 MB (gateb after attn)
  u16* kb   = (u16*)alloc((size_t)M_ * H_ * 2);     // 16 MB (WO partial 0)
  u16* vb   = (u16*)alloc((size_t)M_ * H_ * 2);     // 16 MB (WO partial 1)
  u16* vtb  = (u16*)alloc((size_t)M_ * H_ * 2);     // 16 MB
  u16* attn = (u16*)alloc((size_t)M_ * H_ * 2);     // 16 MB (down partial 1)
  float* x2 = (float*)alloc((size_t)M_ * H_ * 4);   // 32 MB
  float* cosT = (float*)alloc((size_t)L_ * 64 * 4);
  float* sinT = (float*)alloc((size_t)L_ * 64 * 4);
  u16* h2    = h1;   // h1 dead after QKV GEMM
  u16* gateb = qb;   // qb..vtb region dead after flash_attn / WO

  const int nHH4 = (int)(HH / 4), nIH4 = (int)(IH / 4);

  rmsnorm_k<<<M_, 256, 0, stream>>>(x, ln1w, h1);
  rope_tab<<<(L_ * 64) / 256, 256, 0, stream>>>(cosT, sinT, offp);

  // fused QKV: wq/wk/wv stacked -> one N=6144 GEMM, scatter epilogue
  cvt_w<<<nHH4 / 256, 256, 0, stream>>>(wq, wbuf, nHH4);
  cvt_w<<<nHH4 / 256, 256, 0, stream>>>(wk, wbuf + HH, nHH4);
  cvt_w<<<nHH4 / 256, 256, 0, stream>>>(wv, wbuf + 2 * HH, nHH4);
  int nwg_qkv = (M_ / 256) * (3 * H_ / 256);   // 384
  gemm256<EPI_QKV3><<<nwg_qkv, 512, 0, stream>>>(h1, wbuf, M_, 3 * H_, H_,
                                                 H_ / 64, qb, nullptr);

  int nrope = B_ * NH_ * L_ * 64;
  rope_apply<<<nrope / 256, 256, 0, stream>>>(qb, cosT, sinT);
  rope_apply<<<nrope / 256, 256, 0, stream>>>(qb + (size_t)M_ * H_, cosT, sinT);
  vtrans_k<<<dim3(L_ / 64, D_ / 64, B_ * NH_), 256, 0, stream>>>(
      qb + 2 * (size_t)M_ * H_, vtb);

  flash_attn<<<dim3(L_ / 64, NH_, B_), 256, 0, stream>>>(
      qb, qb + (size_t)M_ * H_, vtb, attn);

  // WO: split-K=2 on gemm256 (grid 256 = 1 full round), partials kb/vb,
  // reduce adds residual x -> x2 (fp32)
  cvt_w<<<nHH4 / 256, 256, 0, stream>>>(wo, wbuf, nHH4);
  int nwg_wo = 2 * (M_ / 256) * (H_ / 256);    // 256
  gemm256<EPI_PART><<<nwg_wo, 512, 0, stream>>>(attn, wbuf, M_, H_, H_,
                                                H_ / 128, kb, vb);
  down_reduce<<<(M_ * H_ / 4) / 256, 256, 0, stream>>>(kb, vb, x, x2,
                                                       M_ * H_ / 4);
  rmsnorm_k<<<M_, 256, 0, stream>>>(x2, ln2w, h2);

  // MLP gate/up on the 256^2 kernel (512 blocks each = 2 full rounds)
  int nwg256 = (M_ / 256) * (I_ / 256);
  cvt_w<<<nIH4 / 256, 256, 0, stream>>>(wg, wbuf, nIH4);
  gemm256<EPI_SILU><<<nwg256, 512, 0, stream>>>(h2, wbuf, M_, I_, H_,
                                                H_ / 64, gateb, nullptr);
  cvt_w<<<nIH4 / 256, 256, 0, stream>>>(wu, wbuf, nIH4);
  gemm256<EPI_MUL><<<nwg256, 512, 0, stream>>>(h2, wbuf, M_, I_, H_,
                                               H_ / 64, gateb, nullptr);

  // down-proj: split-K=2 (grid 256 = 1 full round), partials h1/attn, reduce
  cvt_w<<<nIH4 / 256, 256, 0, stream>>>(wd, wbuf, nIH4);
  int nwg_dn = 2 * (M_ / 256) * (H_ / 256);    // 256
  gemm256<EPI_PART><<<nwg_dn, 512, 0, stream>>>(gateb, wbuf, M_, H_, I_,
                                                I_ / 128, h1, attn);
  down_reduce<<<(M_ * H_ / 4) / 256, 256, 0, stream>>>(h1, attn, x2, out,
                                                       M_ * H_ / 4);
}

// Round 12
// 851.619 us; speedup vs baseline: 1.0414x; 1.0018x over previous
//
#include <hip/hip_runtime.h>
#include <stdint.h>

#define B_ 2
#define L_ 2048
#define H_ 2048
#define NH_ 16
#define D_ 128
#define I_ 8192
#define M_ (B_*L_)

typedef unsigned short u16;
typedef __attribute__((ext_vector_type(8))) short bf16x8;
typedef __attribute__((ext_vector_type(4))) float f32x4;

__device__ __forceinline__ u16 f2bf(float f) {
  union { float f; uint32_t u; } c; c.f = f;
  return (u16)((c.u + 0x7fffu + ((c.u >> 16) & 1u)) >> 16);
}
__device__ __forceinline__ float bf2f(u16 h) {
  union { uint32_t u; float f; } c; c.u = ((uint32_t)h) << 16;
  return c.f;
}
// global -> LDS direct DMA, 16B/lane. LDS dest is wave-uniform base + lane*16.
__device__ __forceinline__ void gload16(const void* g, void* l) {
  __builtin_amdgcn_global_load_lds(
      (__attribute__((address_space(1))) void*)g,
      (__attribute__((address_space(3))) void*)l, 16, 0, 0);
}

// ---------------- fp32 -> bf16 conversion ----------------
__global__ void cvt_w(const float* __restrict__ src, u16* __restrict__ dst, int n4) {
  int i = blockIdx.x * blockDim.x + threadIdx.x;
  if (i >= n4) return;
  float4 v = ((const float4*)src)[i];
  ushort4 o;
  o.x = f2bf(v.x); o.y = f2bf(v.y); o.z = f2bf(v.z); o.w = f2bf(v.w);
  ((ushort4*)dst)[i] = o;
}

// ---------------- split-K partial reduce: out = p0 + p1 + res (fp32) --------
__global__ __launch_bounds__(256) void down_reduce(const u16* __restrict__ p0,
                                                   const u16* __restrict__ p1,
                                                   const float* __restrict__ res,
                                                   float* __restrict__ out, int n4) {
  int i = blockIdx.x * blockDim.x + threadIdx.x;
  if (i >= n4) return;
  ushort4 a = ((const ushort4*)p0)[i];
  ushort4 b = ((const ushort4*)p1)[i];
  float4 r = ((const float4*)res)[i];
  float4 o;
  o.x = bf2f(a.x) + bf2f(b.x) + r.x;
  o.y = bf2f(a.y) + bf2f(b.y) + r.y;
  o.z = bf2f(a.z) + bf2f(b.z) + r.z;
  o.w = bf2f(a.w) + bf2f(b.w) + r.w;
  ((float4*)out)[i] = o;
}

// ---------------- RMSNorm: one block per row ----------------
__global__ __launch_bounds__(256) void rmsnorm_k(const float* __restrict__ x,
                                                 const float* __restrict__ w,
                                                 u16* __restrict__ out) {
  int row = blockIdx.x;
  int t = threadIdx.x;
  const float4* xr = (const float4*)(x + (size_t)row * H_);
  float4 a = xr[t * 2], b = xr[t * 2 + 1];
  float s = a.x*a.x + a.y*a.y + a.z*a.z + a.w*a.w
          + b.x*b.x + b.y*b.y + b.z*b.z + b.w*b.w;
  for (int m = 1; m < 64; m <<= 1) s += __shfl_xor(s, m);
  __shared__ float sm[4];
  if ((t & 63) == 0) sm[t >> 6] = s;
  __syncthreads();
  float tot = sm[0] + sm[1] + sm[2] + sm[3];
  float rs = rsqrtf(tot / (float)H_ + 1e-6f);
  const float4* wr = (const float4*)w;
  float4 w0 = wr[t * 2], w1 = wr[t * 2 + 1];
  ushort4 o0, o1;
  o0.x = f2bf(a.x * rs * w0.x); o0.y = f2bf(a.y * rs * w0.y);
  o0.z = f2bf(a.z * rs * w0.z); o0.w = f2bf(a.w * rs * w0.w);
  o1.x = f2bf(b.x * rs * w1.x); o1.y = f2bf(b.y * rs * w1.y);
  o1.z = f2bf(b.z * rs * w1.z); o1.w = f2bf(b.w * rs * w1.w);
  ushort4* orow = (ushort4*)(out + (size_t)row * H_);
  orow[t * 2] = o0; orow[t * 2 + 1] = o1;
}

// ---------------- RoPE tables ----------------
__global__ void rope_tab(float* __restrict__ cosT, float* __restrict__ sinT,
                         const int* __restrict__ offp) {
  int i = blockIdx.x * blockDim.x + threadIdx.x;  // L_*64
  int d = i & 63, l = i >> 6;
  float inv = powf(10000.0f, -(float)d / 64.0f);
  float ang = (float)(l + *offp) * inv;
  cosT[i] = cosf(ang);
  sinT[i] = sinf(ang);
}

// ---------------- RoPE apply, in-place on (B,NH,L,D) bf16 ----------------
__global__ void rope_apply(u16* __restrict__ qk, const float* __restrict__ cosT,
                           const float* __restrict__ sinT) {
  int i = blockIdx.x * blockDim.x + threadIdx.x;  // B_*NH_*L_*64
  int d = i & 63;
  size_t row = (size_t)(i >> 6);
  int l = (int)(row & (L_ - 1));
  u16* p = qk + row * D_;
  float x1 = bf2f(p[d]), x2 = bf2f(p[d + 64]);
  float c = cosT[l * 64 + d], s = sinT[l * 64 + d];
  p[d]      = f2bf(x1 * c - x2 * s);
  p[d + 64] = f2bf(x2 * c + x1 * s);
}

// ---------------- V transpose: (B,NH,L,D) -> (B,NH,D,L) ----------------
__global__ __launch_bounds__(256) void vtrans_k(const u16* __restrict__ v,
                                                u16* __restrict__ vt) {
  __shared__ u16 tile[64][65];
  int l0 = blockIdx.x * 64, d0 = blockIdx.y * 64;
  size_t base = (size_t)blockIdx.z * L_ * D_;
  int t = threadIdx.x;
  int tr = t >> 3, tc = (t & 7) * 8;
  #pragma unroll
  for (int it = 0; it < 2; ++it) {
    int r = tr + it * 32;
    const u16* src = v + base + (size_t)(l0 + r) * D_ + d0 + tc;
    ushort4 u0 = ((const ushort4*)src)[0], u1 = ((const ushort4*)src)[1];
    tile[r][tc + 0] = u0.x; tile[r][tc + 1] = u0.y;
    tile[r][tc + 2] = u0.z; tile[r][tc + 3] = u0.w;
    tile[r][tc + 4] = u1.x; tile[r][tc + 5] = u1.y;
    tile[r][tc + 6] = u1.z; tile[r][tc + 7] = u1.w;
  }
  __syncthreads();
  #pragma unroll
  for (int it = 0; it < 2; ++it) {
    int r = tr + it * 32;
    u16* dst = vt + base + (size_t)(d0 + r) * L_ + l0 + tc;
    ushort4 o0, o1;
    o0.x = tile[tc + 0][r]; o0.y = tile[tc + 1][r];
    o0.z = tile[tc + 2][r]; o0.w = tile[tc + 3][r];
    o1.x = tile[tc + 4][r]; o1.y = tile[tc + 5][r];
    o1.z = tile[tc + 6][r]; o1.w = tile[tc + 7][r];
    ((ushort4*)dst)[0] = o0; ((ushort4*)dst)[1] = o1;
  }
}

#define EPI_SILU 1
#define EPI_MUL 2
#define EPI_PART 4
#define EPI_QKV3 5

// ---------------- GEMM 256x256 8-wave quadrant-phased (r9 structure) ---------
// 512 thr = 8 waves; BK=64; LDS 128KB dbuf; vmcnt(4) counted waits; LDS XOR
// swizzle both-sides (rule #21); column-major wg->(m,n) (r9: FETCH 303->180MB).
// NOTE (r6/r8/r10 post-mortem): MfmaUtil pinned at ~30% by LDS-read pipe
// (192KB frag reads per K-tile per block vs ~620cyc MFMA) — schedule variants
// are null; this is the best-measured variant. Do not re-tune the K-loop.
template <int EPI>
__global__ __launch_bounds__(512, 2)
void gemm256(const u16* __restrict__ A, const u16* __restrict__ Bw,
             int M, int N, int K, int nk,
             u16* __restrict__ outb, u16* __restrict__ outb2) {
  __shared__ __attribute__((aligned(16))) u16 Asm[2][2][8192];
  __shared__ __attribute__((aligned(16))) u16 Bsm[2][2][8192];
  int tid = threadIdx.x;
  int wid = tid >> 6, lane = tid & 63;
  int r16 = lane & 15, g4 = lane >> 4;
  // bijective XCD swizzle (m204)
  int nwg = gridDim.x, bid = blockIdx.x;
  int q8 = nwg >> 3, r8 = nwg & 7, xcd = bid & 7, loc = bid >> 3;
  int wgall = (xcd < r8 ? xcd * (q8 + 1) : r8 * (q8 + 1) + (xcd - r8) * q8) + loc;
  int nwg_geo = (M >> 8) * (N >> 8);
  int ks = wgall / nwg_geo;     // split-K slice (EPI_PART)
  int wg = wgall % nwg_geo;
  int MX = M >> 8;
  int m0 = (wg % MX) * 256;     // column-major: m fastest
  int n0 = (wg / MX) * 256;
  const char* Ab = (const char*)(A + (size_t)ks * nk * 64);
  const char* Bb = (const char*)(Bw + (size_t)ks * nk * 64);
  u16* ob = (EPI == EPI_PART && ks) ? outb2 : outb;

  f32x4 acc[2][2][4][2] = {};
  bf16x8 afr[4][2];      // A frags for current qm
  bf16x8 bfr[2][2][2];   // B frags [qn][nf][kk], both qn held

  // stage half sel of tile kt1: 0:A-h0 1:B-h0 2:B-h1 3:A-h1
  auto STAGE = [&](int kt1, int sel) {
    if (kt1 >= nk) return;
    int buf = kt1 & 1;
    int k0 = kt1 << 6;
    const char* gb; char* lb; int row0;
    if (sel == 0)      { gb = Ab; row0 = m0;       lb = (char*)&Asm[buf][0][0]; }
    else if (sel == 3) { gb = Ab; row0 = m0 + 128; lb = (char*)&Asm[buf][1][0]; }
    else if (sel == 1) { gb = Bb; row0 = n0;       lb = (char*)&Bsm[buf][0][0]; }
    else               { gb = Bb; row0 = n0 + 128; lb = (char*)&Bsm[buf][1][0]; }
    #pragma unroll
    for (int j = 0; j < 2; ++j) {
      int p = j * 8192 + wid * 1024 + lane * 16;
      int r = p >> 7;
      int cb = (p & 127) ^ ((r & 7) << 4);
      gload16(gb + ((size_t)(row0 + r) * K + k0) * 2 + cb,
              lb + j * 8192 + wid * 1024);
    }
  };

  // prologue: tile 0, order A0,B0,B1,A1 (8 loads in flight)
  STAGE(0, 0); STAGE(0, 1); STAGE(0, 2); STAGE(0, 3);

  const int QM[4] = {0, 0, 1, 1};
  const int QN[4] = {0, 1, 1, 0};

  for (int kt = 0; kt < nk; ++kt) {
    int cur = kt & 1;
    #pragma unroll
    for (int ph = 0; ph < 4; ++ph) {
      if (ph < 3) {
        __builtin_amdgcn_sched_barrier(0);
        asm volatile("s_waitcnt vmcnt(4)" ::: "memory");
      }
      __builtin_amdgcn_s_barrier();
      __builtin_amdgcn_sched_barrier(0);
      const int qm = QM[ph], qn = QN[ph];
      if (ph == 0 || ph == 2) {            // (re)load A frags for this qm
        const char* Ah = (const char*)&Asm[cur][qm][0];
        #pragma unroll
        for (int mf = 0; mf < 4; ++mf) {
          int R = (wid >> 2) * 64 + mf * 16 + r16;
          int sw = (R & 7) << 4;
          afr[mf][0] = *(const bf16x8*)(Ah + R * 128 + ((g4 * 16) ^ sw));
          afr[mf][1] = *(const bf16x8*)(Ah + R * 128 + ((64 + g4 * 16) ^ sw));
        }
      }
      if (ph == 0 || ph == 1) {            // load B frags for this qn
        const char* Bh = (const char*)&Bsm[cur][qn][0];
        #pragma unroll
        for (int nf = 0; nf < 2; ++nf) {
          int R = (wid & 3) * 32 + nf * 16 + r16;
          int sw = (R & 7) << 4;
          bfr[qn][nf][0] = *(const bf16x8*)(Bh + R * 128 + ((g4 * 16) ^ sw));
          bfr[qn][nf][1] = *(const bf16x8*)(Bh + R * 128 + ((64 + g4 * 16) ^ sw));
        }
      }
      STAGE(kt + 1, ph);                    // next tile, one half per phase
      __builtin_amdgcn_s_setprio(1);
      #pragma unroll
      for (int mf = 0; mf < 4; ++mf)
        #pragma unroll
        for (int nf = 0; nf < 2; ++nf)
          #pragma unroll
          for (int kk = 0; kk < 2; ++kk)
            acc[qm][qn][mf][nf] = __builtin_amdgcn_mfma_f32_16x16x32_bf16(
                afr[mf][kk], bfr[qn][nf][kk], acc[qm][qn][mf][nf], 0, 0, 0);
      __builtin_amdgcn_s_setprio(0);
    }
  }
  // epilogue
  #pragma unroll
  for (int qm = 0; qm < 2; ++qm)
    #pragma unroll
    for (int qn = 0; qn < 2; ++qn)
      #pragma unroll
      for (int mf = 0; mf < 4; ++mf)
        #pragma unroll
        for (int nf = 0; nf < 2; ++nf)
          #pragma unroll
          for (int rr = 0; rr < 4; ++rr) {
            int row = m0 + qm * 128 + (wid >> 2) * 64 + mf * 16 + g4 * 4 + rr;
            int col = n0 + qn * 128 + (wid & 3) * 32 + nf * 16 + r16;
            float val = acc[qm][qn][mf][nf][rr];
            if (EPI == EPI_SILU) {
              ob[(size_t)row * N + col] = f2bf(val / (1.0f + __expf(-val)));
            } else if (EPI == EPI_MUL) {
              float g = bf2f(ob[(size_t)row * N + col]);
              ob[(size_t)row * N + col] = f2bf(g * val);
            } else if (EPI == EPI_PART) {
              ob[(size_t)row * N + col] = f2bf(val);
            } else if (EPI == EPI_QKV3) {
              int which = col >> 11, within = col & 2047;
              int hh = within >> 7, d = within & 127;
              int bb = row >> 11, l = row & 2047;
              ob[(size_t)which * M_ * H_ +
                 ((((size_t)bb * NH_ + hh) * L_ + l) << 7) + d] = f2bf(val);
            }
          }
}

// ---------------- Flash attention (causal), XOR-swizzled LDS, K/V dbuf ------
// 2-phase pipeline (T3 minimum recipe): STAGE(t+1,buf^1) issued BEFORE the
// compute of tile t; __syncthreads at iter end drains vmcnt AFTER ~600cyc of
// MFMA/softmax (was: drain before compute = full HBM latency exposed).
// Race check: end-of-iter barrier guarantees buf^1 reads (iter t-1) complete
// before iter t re-stages it. LDS 72KB -> 2 blocks/CU.
__global__ __launch_bounds__(256)
void flash_attn(const u16* __restrict__ q, const u16* __restrict__ k,
                const u16* __restrict__ vt, u16* __restrict__ out) {
  __shared__ __attribute__((aligned(16))) u16 Kt[2][64 * 128];
  __shared__ __attribute__((aligned(16))) u16 Vt[2][128 * 64];
  __shared__ __attribute__((aligned(16))) u16 Pl[4][16 * 64];
  int tid = threadIdx.x, w = tid >> 6, lane = tid & 63;
  int r16 = lane & 15, g4 = lane >> 4;
  int b = blockIdx.z, h = blockIdx.y;
  int qt = gridDim.x - 1 - blockIdx.x;   // longest blocks dispatch first
  int q0 = qt * 64;
  size_t bh = (size_t)b * NH_ + h;
  const char* qb = (const char*)(q + bh * L_ * D_);
  const char* kb = (const char*)(k + bh * L_ * D_);
  const char* vb = (const char*)(vt + bh * D_ * L_);
  int qrow = q0 + w * 16 + r16;
  bf16x8 qf[4];
  #pragma unroll
  for (int c = 0; c < 4; ++c)
    qf[c] = *(const bf16x8*)(qb + ((size_t)qrow * 128 + c * 32 + g4 * 8) * 2);
  f32x4 oacc[8] = {};
  float mrow[4], lsum[4];
  #pragma unroll
  for (int r = 0; r < 4; ++r) { mrow[r] = -3.0e38f; lsum[r] = 0.f; }
  int myq = q0 + w * 16 + g4 * 4;
  int ntiles = qt + 1;
  int rsw = (r16 & 7) << 4;
  const float sc = 0.08838834764831845f;

  auto STAGEKV = [&](int t, int buf) {
    if (t >= ntiles) return;
    int kv0 = t * 64;
    #pragma unroll
    for (int i = 0; i < 4; ++i) {
      int uoff = i * 4096 + w * 1024;
      int lin = uoff + lane * 16;
      int krow = lin >> 8;
      int kcol = (lin & 255) ^ ((krow & 7) << 4);
      gload16(kb + (size_t)(kv0 + krow) * 256 + kcol,
              (char*)&Kt[buf][0] + uoff);
      int vrow = lin >> 7;
      int vcol = (lin & 127) ^ ((vrow & 7) << 4);
      gload16(vb + (size_t)vrow * (L_ * 2) + kv0 * 2 + vcol,
              (char*)&Vt[buf][0] + uoff);
    }
  };

  STAGEKV(0, 0);
  __syncthreads();   // implicit vmcnt(0) drain before first compute

  for (int t = 0; t < ntiles; ++t) {
    int buf = t & 1;
    int kv0 = t * 64;
    STAGEKV(t + 1, buf ^ 1);   // prefetch next tile; lands during compute
    const char* Kb = (const char*)&Kt[buf][0];
    const char* Vb = (const char*)&Vt[buf][0];
    // S = Q K^T
    f32x4 s[4] = {};
    __builtin_amdgcn_s_setprio(1);
    #pragma unroll
    for (int c = 0; c < 4; ++c) {
      #pragma unroll
      for (int n = 0; n < 4; ++n) {
        bf16x8 kf = *(const bf16x8*)(Kb + (n * 16 + r16) * 256
                                     + ((c * 64 + g4 * 16) ^ rsw));
        s[n] = __builtin_amdgcn_mfma_f32_16x16x32_bf16(qf[c], kf, s[n], 0, 0, 0);
      }
    }
    __builtin_amdgcn_s_setprio(0);
    // scale + causal mask + online softmax
    #pragma unroll
    for (int r = 0; r < 4; ++r) {
      float rm = -3.0e38f;
      #pragma unroll
      for (int n = 0; n < 4; ++n) {
        float v = s[n][r] * sc;
        int kvi = kv0 + n * 16 + r16;
        if (kvi > myq + r) v = -3.0e38f;
        s[n][r] = v;
        rm = fmaxf(rm, v);
      }
      rm = fmaxf(rm, __shfl_xor(rm, 1));
      rm = fmaxf(rm, __shfl_xor(rm, 2));
      rm = fmaxf(rm, __shfl_xor(rm, 4));
      rm = fmaxf(rm, __shfl_xor(rm, 8));
      float mnew = fmaxf(mrow[r], rm);
      float alpha = __expf(mrow[r] - mnew);
      mrow[r] = mnew;
      lsum[r] *= alpha;
      #pragma unroll
      for (int nf = 0; nf < 8; ++nf) oacc[nf][r] *= alpha;
      int prow = g4 * 4 + r;
      int psw = (prow & 7) << 3;
      #pragma unroll
      for (int n = 0; n < 4; ++n) {
        float pv = __expf(s[n][r] - mnew);
        lsum[r] += pv;
        Pl[w][prow * 64 + ((n * 16 + r16) ^ psw)] = f2bf(pv);
      }
    }
    // wave-internal LDS visibility fence (guide rule #18)
    asm volatile("s_waitcnt lgkmcnt(0)" ::: "memory");
    __builtin_amdgcn_sched_barrier(0);
    // O += P V
    __builtin_amdgcn_s_setprio(1);
    #pragma unroll
    for (int kc = 0; kc < 2; ++kc) {
      bf16x8 pf = *(const bf16x8*)((const char*)&Pl[w][0] + r16 * 128
                                   + ((kc * 64 + g4 * 16) ^ rsw));
      #pragma unroll
      for (int nf = 0; nf < 8; ++nf) {
        bf16x8 vf = *(const bf16x8*)(Vb + (nf * 16 + r16) * 128
                                     + ((kc * 64 + g4 * 16) ^ rsw));
        oacc[nf] = __builtin_amdgcn_mfma_f32_16x16x32_bf16(pf, vf, oacc[nf], 0, 0, 0);
      }
    }
    __builtin_amdgcn_s_setprio(0);
    __syncthreads();   // drains prefetch (vmcnt(0)) + publishes buf^1
  }
  #pragma unroll
  for (int r = 0; r < 4; ++r) {
    float l = lsum[r];
    l += __shfl_xor(l, 1); l += __shfl_xor(l, 2);
    l += __shfl_xor(l, 4); l += __shfl_xor(l, 8);
    float inv = 1.0f / l;
    size_t orow = ((size_t)b * L_ + (myq + r)) * H_ + h * D_;
    #pragma unroll
    for (int nf = 0; nf < 8; ++nf)
      out[orow + nf * 16 + r16] = f2bf(oacc[nf][r] * inv);
  }
}

// ---------------- host orchestration ----------------
extern "C" void kernel_launch(void* const* d_in, const int* in_sizes, int n_in,
                              void* d_out, int out_size, void* d_ws, size_t ws_size,
                              hipStream_t stream) {
  (void)in_sizes; (void)n_in; (void)out_size; (void)ws_size;
  const float* x    = (const float*)d_in[0];
  const float* ln1w = (const float*)d_in[1];
  const float* ln2w = (const float*)d_in[2];
  const float* wq   = (const float*)d_in[3];
  const float* wk   = (const float*)d_in[4];
  const float* wv   = (const float*)d_in[5];
  const float* wo   = (const float*)d_in[6];
  const float* wg   = (const float*)d_in[7];
  const float* wu   = (const float*)d_in[8];
  const float* wd   = (const float*)d_in[9];
  const int*   offp = (const int*)d_in[11];
  float* out = (float*)d_out;

  char* p = (char*)d_ws;
  auto alloc = [&](size_t bytes) {
    char* r = p;
    p += (bytes + 255) & ~(size_t)255;
    return r;
  };
  const size_t HH = (size_t)H_ * H_, IH = (size_t)I_ * H_;
  u16* wbuf = (u16*)alloc(IH * 2);                  // 32 MB, reused
  u16* h1   = (u16*)alloc((size_t)M_ * H_ * 2);     // 16 MB (h2; down partial 0)
  u16* qb   = (u16*)alloc((size_t)M_ * H_ * 2);     // 16 MB (gateb after attn)
  u16* kb   = (u16*)alloc((size_t)M_ * H_ * 2);     // 16 MB (WO partial 0)
  u16* vb   = (u16*)alloc((size_t)M_ * H_ * 2);     // 16 MB (WO partial 1)
  u16* vtb  = (u16*)alloc((size_t)M_ * H_ * 2);     // 16 MB
  u16* attn = (u16*)alloc((size_t)M_ * H_ * 2);     // 16 MB (down partial 1)
  float* x2 = (float*)alloc((size_t)M_ * H_ * 4);   // 32 MB
  float* cosT = (float*)alloc((size_t)L_ * 64 * 4);
  float* sinT = (float*)alloc((size_t)L_ * 64 * 4);
  u16* h2    = h1;   // h1 dead after QKV GEMM
  u16* gateb = qb;   // qb..vtb region dead after flash_attn / WO

  const int nHH4 = (int)(HH / 4), nIH4 = (int)(IH / 4);

  rmsnorm_k<<<M_, 256, 0, stream>>>(x, ln1w, h1);
  rope_tab<<<(L_ * 64) / 256, 256, 0, stream>>>(cosT, sinT, offp);

  // fused QKV: wq/wk/wv stacked -> one N=6144 GEMM, scatter epilogue
  cvt_w<<<nHH4 / 256, 256, 0, stream>>>(wq, wbuf, nHH4);
  cvt_w<<<nHH4 / 256, 256, 0, stream>>>(wk, wbuf + HH, nHH4);
  cvt_w<<<nHH4 / 256, 256, 0, stream>>>(wv, wbuf + 2 * HH, nHH4);
  int nwg_qkv = (M_ / 256) * (3 * H_ / 256);   // 384
  gemm256<EPI_QKV3><<<nwg_qkv, 512, 0, stream>>>(h1, wbuf, M_, 3 * H_, H_,
                                                 H_ / 64, qb, nullptr);

  int nrope = B_ * NH_ * L_ * 64;
  rope_apply<<<nrope / 256, 256, 0, stream>>>(qb, cosT, sinT);
  rope_apply<<<nrope / 256, 256, 0, stream>>>(qb + (size_t)M_ * H_, cosT, sinT);
  vtrans_k<<<dim3(L_ / 64, D_ / 64, B_ * NH_), 256, 0, stream>>>(
      qb + 2 * (size_t)M_ * H_, vtb);

  flash_attn<<<dim3(L_ / 64, NH_, B_), 256, 0, stream>>>(
      qb, qb + (size_t)M_ * H_, vtb, attn);

  // WO: split-K=2 on gemm256 (grid 256 = 1 full round), partials kb/vb,
  // reduce adds residual x -> x2 (fp32)
  cvt_w<<<nHH4 / 256, 256, 0, stream>>>(wo, wbuf, nHH4);
  int nwg_wo = 2 * (M_ / 256) * (H_ / 256);    // 256
  gemm256<EPI_PART><<<nwg_wo, 512, 0, stream>>>(attn, wbuf, M_, H_, H_,
                                                H_ / 128, kb, vb);
  down_reduce<<<(M_ * H_ / 4) / 256, 256, 0, stream>>>(kb, vb, x, x2,
                                                       M_ * H_ / 4);
  rmsnorm_k<<<M_, 256, 0, stream>>>(x2, ln2w, h2);

  // MLP gate/up on the 256^2 kernel (512 blocks each = 2 full rounds)
  int nwg256 = (M_ / 256) * (I_ / 256);
  cvt_w<<<nIH4 / 256, 256, 0, stream>>>(wg, wbuf, nIH4);
  gemm256<EPI_SILU><<<nwg256, 512, 0, stream>>>(h2, wbuf, M_, I_, H_,
                                                H_ / 64, gateb, nullptr);
  cvt_w<<<nIH4 / 256, 256, 0, stream>>>(wu, wbuf, nIH4);
  gemm256<EPI_MUL><<<nwg256, 512, 0, stream>>>(h2, wbuf, M_, I_, H_,
                                               H_ / 64, gateb, nullptr);

  // down-proj: split-K=2 (grid 256 = 1 full round), partials h1/attn, reduce
  cvt_w<<<nIH4 / 256, 256, 0, stream>>>(wd, wbuf, nIH4);
  int nwg_dn = 2 * (M_ / 256) * (H_ / 256);    // 256
  gemm256<EPI_PART><<<nwg_dn, 512, 0, stream>>>(gateb, wbuf, M_, H_, I_,
                                                I_ / 128, h1, attn);
  down_reduce<<<(M_ * H_ / 4) / 256, 256, 0, stream>>>(h1, attn, x2, out,
                                                       M_ * H_ / 4);
}

// Round 13
// 832.897 us; speedup vs baseline: 1.0648x; 1.0225x over previous
//
#include <hip/hip_runtime.h>
#include <stdint.h>

#define B_ 2
#define L_ 2048
#define H_ 2048
#define NH_ 16
#define D_ 128
#define I_ 8192
#define M_ (B_*L_)

typedef unsigned short u16;
typedef __attribute__((ext_vector_type(8))) short bf16x8;
typedef __attribute__((ext_vector_type(4))) float f32x4;

__device__ __forceinline__ u16 f2bf(float f) {
  union { float f; uint32_t u; } c; c.f = f;
  return (u16)((c.u + 0x7fffu + ((c.u >> 16) & 1u)) >> 16);
}
__device__ __forceinline__ float bf2f(u16 h) {
  union { uint32_t u; float f; } c; c.u = ((uint32_t)h) << 16;
  return c.f;
}
// global -> LDS direct DMA, 16B/lane. LDS dest is wave-uniform base + lane*16.
__device__ __forceinline__ void gload16(const void* g, void* l) {
  __builtin_amdgcn_global_load_lds(
      (__attribute__((address_space(1))) void*)g,
      (__attribute__((address_space(3))) void*)l, 16, 0, 0);
}

// ---------------- fp32 -> bf16 conversion ----------------
__global__ void cvt_w(const float* __restrict__ src, u16* __restrict__ dst, int n4) {
  int i = blockIdx.x * blockDim.x + threadIdx.x;
  if (i >= n4) return;
  float4 v = ((const float4*)src)[i];
  ushort4 o;
  o.x = f2bf(v.x); o.y = f2bf(v.y); o.z = f2bf(v.z); o.w = f2bf(v.w);
  ((ushort4*)dst)[i] = o;
}

// ---------------- split-K partial reduce: out = p0 + p1 + res (fp32) --------
__global__ __launch_bounds__(256) void down_reduce(const u16* __restrict__ p0,
                                                   const u16* __restrict__ p1,
                                                   const float* __restrict__ res,
                                                   float* __restrict__ out, int n4) {
  int i = blockIdx.x * blockDim.x + threadIdx.x;
  if (i >= n4) return;
  ushort4 a = ((const ushort4*)p0)[i];
  ushort4 b = ((const ushort4*)p1)[i];
  float4 r = ((const float4*)res)[i];
  float4 o;
  o.x = bf2f(a.x) + bf2f(b.x) + r.x;
  o.y = bf2f(a.y) + bf2f(b.y) + r.y;
  o.z = bf2f(a.z) + bf2f(b.z) + r.z;
  o.w = bf2f(a.w) + bf2f(b.w) + r.w;
  ((float4*)out)[i] = o;
}

// ---------------- RMSNorm: one block per row ----------------
__global__ __launch_bounds__(256) void rmsnorm_k(const float* __restrict__ x,
                                                 const float* __restrict__ w,
                                                 u16* __restrict__ out) {
  int row = blockIdx.x;
  int t = threadIdx.x;
  const float4* xr = (const float4*)(x + (size_t)row * H_);
  float4 a = xr[t * 2], b = xr[t * 2 + 1];
  float s = a.x*a.x + a.y*a.y + a.z*a.z + a.w*a.w
          + b.x*b.x + b.y*b.y + b.z*b.z + b.w*b.w;
  for (int m = 1; m < 64; m <<= 1) s += __shfl_xor(s, m);
  __shared__ float sm[4];
  if ((t & 63) == 0) sm[t >> 6] = s;
  __syncthreads();
  float tot = sm[0] + sm[1] + sm[2] + sm[3];
  float rs = rsqrtf(tot / (float)H_ + 1e-6f);
  const float4* wr = (const float4*)w;
  float4 w0 = wr[t * 2], w1 = wr[t * 2 + 1];
  ushort4 o0, o1;
  o0.x = f2bf(a.x * rs * w0.x); o0.y = f2bf(a.y * rs * w0.y);
  o0.z = f2bf(a.z * rs * w0.z); o0.w = f2bf(a.w * rs * w0.w);
  o1.x = f2bf(b.x * rs * w1.x); o1.y = f2bf(b.y * rs * w1.y);
  o1.z = f2bf(b.z * rs * w1.z); o1.w = f2bf(b.w * rs * w1.w);
  ushort4* orow = (ushort4*)(out + (size_t)row * H_);
  orow[t * 2] = o0; orow[t * 2 + 1] = o1;
}

// ---------------- RoPE tables ----------------
__global__ void rope_tab(float* __restrict__ cosT, float* __restrict__ sinT,
                         const int* __restrict__ offp) {
  int i = blockIdx.x * blockDim.x + threadIdx.x;  // L_*64
  int d = i & 63, l = i >> 6;
  float inv = powf(10000.0f, -(float)d / 64.0f);
  float ang = (float)(l + *offp) * inv;
  cosT[i] = cosf(ang);
  sinT[i] = sinf(ang);
}

// ---------------- RoPE apply, in-place on (B,NH,L,D) bf16 ----------------
__global__ void rope_apply(u16* __restrict__ qk, const float* __restrict__ cosT,
                           const float* __restrict__ sinT) {
  int i = blockIdx.x * blockDim.x + threadIdx.x;  // B_*NH_*L_*64
  int d = i & 63;
  size_t row = (size_t)(i >> 6);
  int l = (int)(row & (L_ - 1));
  u16* p = qk + row * D_;
  float x1 = bf2f(p[d]), x2 = bf2f(p[d + 64]);
  float c = cosT[l * 64 + d], s = sinT[l * 64 + d];
  p[d]      = f2bf(x1 * c - x2 * s);
  p[d + 64] = f2bf(x2 * c + x1 * s);
}

// ---------------- V transpose: (B,NH,L,D) -> (B,NH,D,L) ----------------
__global__ __launch_bounds__(256) void vtrans_k(const u16* __restrict__ v,
                                                u16* __restrict__ vt) {
  __shared__ u16 tile[64][65];
  int l0 = blockIdx.x * 64, d0 = blockIdx.y * 64;
  size_t base = (size_t)blockIdx.z * L_ * D_;
  int t = threadIdx.x;
  int tr = t >> 3, tc = (t & 7) * 8;
  #pragma unroll
  for (int it = 0; it < 2; ++it) {
    int r = tr + it * 32;
    const u16* src = v + base + (size_t)(l0 + r) * D_ + d0 + tc;
    ushort4 u0 = ((const ushort4*)src)[0], u1 = ((const ushort4*)src)[1];
    tile[r][tc + 0] = u0.x; tile[r][tc + 1] = u0.y;
    tile[r][tc + 2] = u0.z; tile[r][tc + 3] = u0.w;
    tile[r][tc + 4] = u1.x; tile[r][tc + 5] = u1.y;
    tile[r][tc + 6] = u1.z; tile[r][tc + 7] = u1.w;
  }
  __syncthreads();
  #pragma unroll
  for (int it = 0; it < 2; ++it) {
    int r = tr + it * 32;
    u16* dst = vt + base + (size_t)(d0 + r) * L_ + l0 + tc;
    ushort4 o0, o1;
    o0.x = tile[tc + 0][r]; o0.y = tile[tc + 1][r];
    o0.z = tile[tc + 2][r]; o0.w = tile[tc + 3][r];
    o1.x = tile[tc + 4][r]; o1.y = tile[tc + 5][r];
    o1.z = tile[tc + 6][r]; o1.w = tile[tc + 7][r];
    ((ushort4*)dst)[0] = o0; ((ushort4*)dst)[1] = o1;
  }
}

#define EPI_SILU 1
#define EPI_MUL 2
#define EPI_PART 4
#define EPI_QKV3 5
#define EPI_GLU 6

// ---------------- GEMM 256x256 8-wave quadrant-phased (r9 structure) ---------
// 512 thr = 8 waves; BK=64; LDS 128KB dbuf; vmcnt(4) counted waits; LDS XOR
// swizzle both-sides (rule #21); column-major wg->(m,n).
// FROZEN K-loop (r6/r8/r10: schedule variants null at MfmaUtil ~30-33%).
// EPI_GLU: B-rows = 128 gate rows (Bw) + 128 up rows (Bw2) for the SAME
// 128 output cols -> silu(gate)*up computed in-register, single write.
template <int EPI>
__global__ __launch_bounds__(512, 2)
void gemm256(const u16* __restrict__ A, const u16* __restrict__ Bw,
             int M, int N, int K, int nk,
             u16* __restrict__ outb, u16* __restrict__ outb2,
             const u16* __restrict__ Bw2) {
  __shared__ __attribute__((aligned(16))) u16 Asm[2][2][8192];
  __shared__ __attribute__((aligned(16))) u16 Bsm[2][2][8192];
  int tid = threadIdx.x;
  int wid = tid >> 6, lane = tid & 63;
  int r16 = lane & 15, g4 = lane >> 4;
  // bijective XCD swizzle (m204)
  int nwg = gridDim.x, bid = blockIdx.x;
  int q8 = nwg >> 3, r8 = nwg & 7, xcd = bid & 7, loc = bid >> 3;
  int wgall = (xcd < r8 ? xcd * (q8 + 1) : r8 * (q8 + 1) + (xcd - r8) * q8) + loc;
  int nwg_geo = (M >> 8) * ((EPI == EPI_GLU) ? (N >> 7) : (N >> 8));
  int ks = wgall / nwg_geo;     // split-K slice (EPI_PART)
  int wg = wgall % nwg_geo;
  int MX = M >> 8;
  int m0 = (wg % MX) * 256;     // column-major: m fastest
  int n0 = (wg / MX) * ((EPI == EPI_GLU) ? 128 : 256);
  const char* Ab = (const char*)(A + (size_t)ks * nk * 64);
  const char* Bb = (const char*)(Bw + (size_t)ks * nk * 64);
  const char* Bb2 = (const char*)Bw2;
  u16* ob = (EPI == EPI_PART && ks) ? outb2 : outb;

  f32x4 acc[2][2][4][2] = {};
  bf16x8 afr[4][2];      // A frags for current qm
  bf16x8 bfr[2][2][2];   // B frags [qn][nf][kk], both qn held

  // stage half sel of tile kt1: 0:A-h0 1:B-h0 2:B-h1 3:A-h1
  auto STAGE = [&](int kt1, int sel) {
    if (kt1 >= nk) return;
    int buf = kt1 & 1;
    int k0 = kt1 << 6;
    const char* gb; char* lb; int row0;
    if (sel == 0)      { gb = Ab; row0 = m0;       lb = (char*)&Asm[buf][0][0]; }
    else if (sel == 3) { gb = Ab; row0 = m0 + 128; lb = (char*)&Asm[buf][1][0]; }
    else if (sel == 1) { gb = Bb; row0 = n0;       lb = (char*)&Bsm[buf][0][0]; }
    else               { gb = (EPI == EPI_GLU) ? Bb2 : Bb;
                         row0 = (EPI == EPI_GLU) ? n0 : n0 + 128;
                         lb = (char*)&Bsm[buf][1][0]; }
    #pragma unroll
    for (int j = 0; j < 2; ++j) {
      int p = j * 8192 + wid * 1024 + lane * 16;
      int r = p >> 7;
      int cb = (p & 127) ^ ((r & 7) << 4);
      gload16(gb + ((size_t)(row0 + r) * K + k0) * 2 + cb,
              lb + j * 8192 + wid * 1024);
    }
  };

  // prologue: tile 0, order A0,B0,B1,A1 (8 loads in flight)
  STAGE(0, 0); STAGE(0, 1); STAGE(0, 2); STAGE(0, 3);

  const int QM[4] = {0, 0, 1, 1};
  const int QN[4] = {0, 1, 1, 0};

  for (int kt = 0; kt < nk; ++kt) {
    int cur = kt & 1;
    #pragma unroll
    for (int ph = 0; ph < 4; ++ph) {
      if (ph < 3) {
        __builtin_amdgcn_sched_barrier(0);
        asm volatile("s_waitcnt vmcnt(4)" ::: "memory");
      }
      __builtin_amdgcn_s_barrier();
      __builtin_amdgcn_sched_barrier(0);
      const int qm = QM[ph], qn = QN[ph];
      if (ph == 0 || ph == 2) {            // (re)load A frags for this qm
        const char* Ah = (const char*)&Asm[cur][qm][0];
        #pragma unroll
        for (int mf = 0; mf < 4; ++mf) {
          int R = (wid >> 2) * 64 + mf * 16 + r16;
          int sw = (R & 7) << 4;
          afr[mf][0] = *(const bf16x8*)(Ah + R * 128 + ((g4 * 16) ^ sw));
          afr[mf][1] = *(const bf16x8*)(Ah + R * 128 + ((64 + g4 * 16) ^ sw));
        }
      }
      if (ph == 0 || ph == 1) {            // load B frags for this qn
        const char* Bh = (const char*)&Bsm[cur][qn][0];
        #pragma unroll
        for (int nf = 0; nf < 2; ++nf) {
          int R = (wid & 3) * 32 + nf * 16 + r16;
          int sw = (R & 7) << 4;
          bfr[qn][nf][0] = *(const bf16x8*)(Bh + R * 128 + ((g4 * 16) ^ sw));
          bfr[qn][nf][1] = *(const bf16x8*)(Bh + R * 128 + ((64 + g4 * 16) ^ sw));
        }
      }
      STAGE(kt + 1, ph);                    // next tile, one half per phase
      __builtin_amdgcn_s_setprio(1);
      #pragma unroll
      for (int mf = 0; mf < 4; ++mf)
        #pragma unroll
        for (int nf = 0; nf < 2; ++nf)
          #pragma unroll
          for (int kk = 0; kk < 2; ++kk)
            acc[qm][qn][mf][nf] = __builtin_amdgcn_mfma_f32_16x16x32_bf16(
                afr[mf][kk], bfr[qn][nf][kk], acc[qm][qn][mf][nf], 0, 0, 0);
      __builtin_amdgcn_s_setprio(0);
    }
  }
  // epilogue
  if (EPI == EPI_GLU) {
    #pragma unroll
    for (int qm = 0; qm < 2; ++qm)
      #pragma unroll
      for (int mf = 0; mf < 4; ++mf)
        #pragma unroll
        for (int nf = 0; nf < 2; ++nf)
          #pragma unroll
          for (int rr = 0; rr < 4; ++rr) {
            int row = m0 + qm * 128 + (wid >> 2) * 64 + mf * 16 + g4 * 4 + rr;
            int col = n0 + (wid & 3) * 32 + nf * 16 + r16;
            float g = acc[qm][0][mf][nf][rr];
            float u = acc[qm][1][mf][nf][rr];
            float sg = g / (1.0f + __expf(-g));
            outb[(size_t)row * N + col] = f2bf(sg * u);
          }
    return;
  }
  #pragma unroll
  for (int qm = 0; qm < 2; ++qm)
    #pragma unroll
    for (int qn = 0; qn < 2; ++qn)
      #pragma unroll
      for (int mf = 0; mf < 4; ++mf)
        #pragma unroll
        for (int nf = 0; nf < 2; ++nf)
          #pragma unroll
          for (int rr = 0; rr < 4; ++rr) {
            int row = m0 + qm * 128 + (wid >> 2) * 64 + mf * 16 + g4 * 4 + rr;
            int col = n0 + qn * 128 + (wid & 3) * 32 + nf * 16 + r16;
            float val = acc[qm][qn][mf][nf][rr];
            if (EPI == EPI_SILU) {
              ob[(size_t)row * N + col] = f2bf(val / (1.0f + __expf(-val)));
            } else if (EPI == EPI_MUL) {
              float g = bf2f(ob[(size_t)row * N + col]);
              ob[(size_t)row * N + col] = f2bf(g * val);
            } else if (EPI == EPI_PART) {
              ob[(size_t)row * N + col] = f2bf(val);
            } else if (EPI == EPI_QKV3) {
              int which = col >> 11, within = col & 2047;
              int hh = within >> 7, d = within & 127;
              int bb = row >> 11, l = row & 2047;
              ob[(size_t)which * M_ * H_ +
                 ((((size_t)bb * NH_ + hh) * L_ + l) << 7) + d] = f2bf(val);
            }
          }
}

// ---------------- Flash attention (causal), QBLK=128, K/V dbuf --------------
// 4 waves, each owns 32 q-rows (2x 16-row fragments). K/V staged ONCE per
// 128 q-rows (2x traffic amortization vs QBLK=64) and prefetched (dbuf).
// LDS 80KB -> exactly 2 blocks/CU. XOR swizzle byte^=((row&7)<<4) both-sides.
__global__ __launch_bounds__(256)
void flash_attn(const u16* __restrict__ q, const u16* __restrict__ k,
                const u16* __restrict__ vt, u16* __restrict__ out) {
  __shared__ __attribute__((aligned(16))) u16 Kt[2][64 * 128];
  __shared__ __attribute__((aligned(16))) u16 Vt[2][128 * 64];
  __shared__ __attribute__((aligned(16))) u16 Pl[4][32 * 64];
  int tid = threadIdx.x, w = tid >> 6, lane = tid & 63;
  int r16 = lane & 15, g4 = lane >> 4;
  int b = blockIdx.z, h = blockIdx.y;
  int qt = gridDim.x - 1 - blockIdx.x;   // longest blocks dispatch first
  int q0 = qt * 128;
  size_t bh = (size_t)b * NH_ + h;
  const char* qb = (const char*)(q + bh * L_ * D_);
  const char* kb = (const char*)(k + bh * L_ * D_);
  const char* vb = (const char*)(vt + bh * D_ * L_);
  bf16x8 qf[2][4];
  #pragma unroll
  for (int rf = 0; rf < 2; ++rf) {
    int qrow = q0 + w * 32 + rf * 16 + r16;
    #pragma unroll
    for (int c = 0; c < 4; ++c)
      qf[rf][c] = *(const bf16x8*)(qb + ((size_t)qrow * 128 + c * 32 + g4 * 8) * 2);
  }
  f32x4 oacc[2][8] = {};
  float mrow[2][4], lsum[2][4];
  #pragma unroll
  for (int rf = 0; rf < 2; ++rf)
    #pragma unroll
    for (int r = 0; r < 4; ++r) { mrow[rf][r] = -3.0e38f; lsum[rf][r] = 0.f; }
  int myq0 = q0 + w * 32 + g4 * 4;   // rf=1 adds +16
  int ntiles = 2 * qt + 2;
  int rsw = (r16 & 7) << 4;
  const float sc = 0.08838834764831845f;

  auto STAGEKV = [&](int t, int buf) {
    if (t >= ntiles) return;
    int kv0 = t * 64;
    #pragma unroll
    for (int i = 0; i < 4; ++i) {
      int uoff = i * 4096 + w * 1024;
      int lin = uoff + lane * 16;
      int krow = lin >> 8;
      int kcol = (lin & 255) ^ ((krow & 7) << 4);
      gload16(kb + (size_t)(kv0 + krow) * 256 + kcol,
              (char*)&Kt[buf][0] + uoff);
      int vrow = lin >> 7;
      int vcol = (lin & 127) ^ ((vrow & 7) << 4);
      gload16(vb + (size_t)vrow * (L_ * 2) + kv0 * 2 + vcol,
              (char*)&Vt[buf][0] + uoff);
    }
  };

  STAGEKV(0, 0);
  __syncthreads();

  for (int t = 0; t < ntiles; ++t) {
    int buf = t & 1;
    int kv0 = t * 64;
    STAGEKV(t + 1, buf ^ 1);   // prefetch; lands during compute
    const char* Kb = (const char*)&Kt[buf][0];
    const char* Vb = (const char*)&Vt[buf][0];
    // S = Q K^T for both 16-row fragments (K frags shared)
    f32x4 s[2][4] = {};
    __builtin_amdgcn_s_setprio(1);
    #pragma unroll
    for (int c = 0; c < 4; ++c) {
      #pragma unroll
      for (int n = 0; n < 4; ++n) {
        bf16x8 kf = *(const bf16x8*)(Kb + (n * 16 + r16) * 256
                                     + ((c * 64 + g4 * 16) ^ rsw));
        s[0][n] = __builtin_amdgcn_mfma_f32_16x16x32_bf16(qf[0][c], kf, s[0][n], 0, 0, 0);
        s[1][n] = __builtin_amdgcn_mfma_f32_16x16x32_bf16(qf[1][c], kf, s[1][n], 0, 0, 0);
      }
    }
    __builtin_amdgcn_s_setprio(0);
    // scale + causal mask + online softmax (per fragment)
    #pragma unroll
    for (int rf = 0; rf < 2; ++rf) {
      int myq = myq0 + rf * 16;
      #pragma unroll
      for (int r = 0; r < 4; ++r) {
        float rm = -3.0e38f;
        #pragma unroll
        for (int n = 0; n < 4; ++n) {
          float v = s[rf][n][r] * sc;
          int kvi = kv0 + n * 16 + r16;
          if (kvi > myq + r) v = -3.0e38f;
          s[rf][n][r] = v;
          rm = fmaxf(rm, v);
        }
        rm = fmaxf(rm, __shfl_xor(rm, 1));
        rm = fmaxf(rm, __shfl_xor(rm, 2));
        rm = fmaxf(rm, __shfl_xor(rm, 4));
        rm = fmaxf(rm, __shfl_xor(rm, 8));
        float mnew = fmaxf(mrow[rf][r], rm);
        float alpha = __expf(mrow[rf][r] - mnew);
        mrow[rf][r] = mnew;
        lsum[rf][r] *= alpha;
        #pragma unroll
        for (int nf = 0; nf < 8; ++nf) oacc[rf][nf][r] *= alpha;
        int prow = rf * 16 + g4 * 4 + r;
        int psw = (prow & 7) << 3;
        #pragma unroll
        for (int n = 0; n < 4; ++n) {
          float pv = __expf(s[rf][n][r] - mnew);
          lsum[rf][r] += pv;
          Pl[w][prow * 64 + ((n * 16 + r16) ^ psw)] = f2bf(pv);
        }
      }
    }
    // wave-internal LDS visibility fence (guide rule #18)
    asm volatile("s_waitcnt lgkmcnt(0)" ::: "memory");
    __builtin_amdgcn_sched_barrier(0);
    // O += P V (V frags shared across fragments)
    __builtin_amdgcn_s_setprio(1);
    #pragma unroll
    for (int kc = 0; kc < 2; ++kc) {
      bf16x8 pf0 = *(const bf16x8*)((const char*)&Pl[w][0] + r16 * 128
                                    + ((kc * 64 + g4 * 16) ^ rsw));
      bf16x8 pf1 = *(const bf16x8*)((const char*)&Pl[w][0] + (16 + r16) * 128
                                    + ((kc * 64 + g4 * 16) ^ rsw));
      #pragma unroll
      for (int nf = 0; nf < 8; ++nf) {
        bf16x8 vf = *(const bf16x8*)(Vb + (nf * 16 + r16) * 128
                                     + ((kc * 64 + g4 * 16) ^ rsw));
        oacc[0][nf] = __builtin_amdgcn_mfma_f32_16x16x32_bf16(pf0, vf, oacc[0][nf], 0, 0, 0);
        oacc[1][nf] = __builtin_amdgcn_mfma_f32_16x16x32_bf16(pf1, vf, oacc[1][nf], 0, 0, 0);
      }
    }
    __builtin_amdgcn_s_setprio(0);
    __syncthreads();   // drains prefetch (vmcnt(0)) + publishes buf^1
  }
  #pragma unroll
  for (int rf = 0; rf < 2; ++rf) {
    #pragma unroll
    for (int r = 0; r < 4; ++r) {
      float l = lsum[rf][r];
      l += __shfl_xor(l, 1); l += __shfl_xor(l, 2);
      l += __shfl_xor(l, 4); l += __shfl_xor(l, 8);
      float inv = 1.0f / l;
      size_t orow = ((size_t)b * L_ + (myq0 + rf * 16 + r)) * H_ + h * D_;
      #pragma unroll
      for (int nf = 0; nf < 8; ++nf)
        out[orow + nf * 16 + r16] = f2bf(oacc[rf][nf][r] * inv);
    }
  }
}

// ---------------- host orchestration ----------------
extern "C" void kernel_launch(void* const* d_in, const int* in_sizes, int n_in,
                              void* d_out, int out_size, void* d_ws, size_t ws_size,
                              hipStream_t stream) {
  (void)in_sizes; (void)n_in; (void)out_size;
  const float* x    = (const float*)d_in[0];
  const float* ln1w = (const float*)d_in[1];
  const float* ln2w = (const float*)d_in[2];
  const float* wq   = (const float*)d_in[3];
  const float* wk   = (const float*)d_in[4];
  const float* wv   = (const float*)d_in[5];
  const float* wo   = (const float*)d_in[6];
  const float* wg   = (const float*)d_in[7];
  const float* wu   = (const float*)d_in[8];
  const float* wd   = (const float*)d_in[9];
  const int*   offp = (const int*)d_in[11];
  float* out = (float*)d_out;

  char* p = (char*)d_ws;
  auto alloc = [&](size_t bytes) {
    char* r = p;
    p += (bytes + 255) & ~(size_t)255;
    return r;
  };
  const size_t HH = (size_t)H_ * H_, IH = (size_t)I_ * H_;
  u16* wbuf = (u16*)alloc(IH * 2);                  // 32 MB, reused
  u16* h1   = (u16*)alloc((size_t)M_ * H_ * 2);     // 16 MB (h2; down partial 0)
  u16* qb   = (u16*)alloc((size_t)M_ * H_ * 2);     // 16 MB (gateb after attn)
  u16* kb   = (u16*)alloc((size_t)M_ * H_ * 2);     // 16 MB (WO partial 0)
  u16* vb   = (u16*)alloc((size_t)M_ * H_ * 2);     // 16 MB (WO partial 1)
  u16* vtb  = (u16*)alloc((size_t)M_ * H_ * 2);     // 16 MB
  u16* attn = (u16*)alloc((size_t)M_ * H_ * 2);     // 16 MB (down partial 1)
  float* x2 = (float*)alloc((size_t)M_ * H_ * 4);   // 32 MB
  float* cosT = (float*)alloc((size_t)L_ * 64 * 4);
  float* sinT = (float*)alloc((size_t)L_ * 64 * 4);
  u16* h2    = h1;   // h1 dead after QKV GEMM
  u16* gateb = qb;   // qb..vtb region dead after flash_attn / WO
  // optional second weight buffer for fused GLU (needs +32MB)
  u16* wu_b = (u16*)alloc(IH * 2);
  bool fused_glu = ((char*)wu_b + IH * 2) <= ((char*)d_ws + ws_size);

  const int nHH4 = (int)(HH / 4), nIH4 = (int)(IH / 4);

  rmsnorm_k<<<M_, 256, 0, stream>>>(x, ln1w, h1);
  rope_tab<<<(L_ * 64) / 256, 256, 0, stream>>>(cosT, sinT, offp);

  // fused QKV: wq/wk/wv stacked -> one N=6144 GEMM, scatter epilogue
  cvt_w<<<nHH4 / 256, 256, 0, stream>>>(wq, wbuf, nHH4);
  cvt_w<<<nHH4 / 256, 256, 0, stream>>>(wk, wbuf + HH, nHH4);
  cvt_w<<<nHH4 / 256, 256, 0, stream>>>(wv, wbuf + 2 * HH, nHH4);
  int nwg_qkv = (M_ / 256) * (3 * H_ / 256);   // 384
  gemm256<EPI_QKV3><<<nwg_qkv, 512, 0, stream>>>(h1, wbuf, M_, 3 * H_, H_,
                                                 H_ / 64, qb, nullptr, nullptr);

  int nrope = B_ * NH_ * L_ * 64;
  rope_apply<<<nrope / 256, 256, 0, stream>>>(qb, cosT, sinT);
  rope_apply<<<nrope / 256, 256, 0, stream>>>(qb + (size_t)M_ * H_, cosT, sinT);
  vtrans_k<<<dim3(L_ / 64, D_ / 64, B_ * NH_), 256, 0, stream>>>(
      qb + 2 * (size_t)M_ * H_, vtb);

  flash_attn<<<dim3(L_ / 128, NH_, B_), 256, 0, stream>>>(
      qb, qb + (size_t)M_ * H_, vtb, attn);

  // WO: split-K=2 on gemm256, partials kb/vb, reduce adds residual x -> x2
  cvt_w<<<nHH4 / 256, 256, 0, stream>>>(wo, wbuf, nHH4);
  int nwg_wo = 2 * (M_ / 256) * (H_ / 256);    // 256
  gemm256<EPI_PART><<<nwg_wo, 512, 0, stream>>>(attn, wbuf, M_, H_, H_,
                                                H_ / 128, kb, vb, nullptr);
  down_reduce<<<(M_ * H_ / 4) / 256, 256, 0, stream>>>(kb, vb, x, x2,
                                                       M_ * H_ / 4);
  rmsnorm_k<<<M_, 256, 0, stream>>>(x2, ln2w, h2);

  if (fused_glu) {
    // fused gate+up: one pass, silu(g)*u in-register (no RMW traffic)
    cvt_w<<<nIH4 / 256, 256, 0, stream>>>(wg, wbuf, nIH4);
    cvt_w<<<nIH4 / 256, 256, 0, stream>>>(wu, wu_b, nIH4);
    int nwg_glu = (M_ / 256) * (I_ / 128);     // 16*64 = 1024
    gemm256<EPI_GLU><<<nwg_glu, 512, 0, stream>>>(h2, wbuf, M_, I_, H_,
                                                  H_ / 64, gateb, nullptr, wu_b);
  } else {
    int nwg256 = (M_ / 256) * (I_ / 256);
    cvt_w<<<nIH4 / 256, 256, 0, stream>>>(wg, wbuf, nIH4);
    gemm256<EPI_SILU><<<nwg256, 512, 0, stream>>>(h2, wbuf, M_, I_, H_,
                                                  H_ / 64, gateb, nullptr, nullptr);
    cvt_w<<<nIH4 / 256, 256, 0, stream>>>(wu, wbuf, nIH4);
    gemm256<EPI_MUL><<<nwg256, 512, 0, stream>>>(h2, wbuf, M_, I_, H_,
                                                 H_ / 64, gateb, nullptr, nullptr);
  }

  // down-proj: split-K=2, partials h1/attn, reduce adds residual x2 -> out
  cvt_w<<<nIH4 / 256, 256, 0, stream>>>(wd, wbuf, nIH4);
  int nwg_dn = 2 * (M_ / 256) * (H_ / 256);    // 256
  gemm256<EPI_PART><<<nwg_dn, 512, 0, stream>>>(gateb, wbuf, M_, H_, I_,
                                                I_ / 128, h1, attn, nullptr);
  down_reduce<<<(M_ * H_ / 4) / 256, 256, 0, stream>>>(h1, attn, x2, out,
                                                       M_ * H_ / 4);
}

// Round 14
// 794.701 us; speedup vs baseline: 1.1160x; 1.0481x over previous
//
#include <hip/hip_runtime.h>
#include <stdint.h>

#define B_ 2
#define L_ 2048
#define H_ 2048
#define NH_ 16
#define D_ 128
#define I_ 8192
#define M_ (B_*L_)

typedef unsigned short u16;
typedef __attribute__((ext_vector_type(8))) short bf16x8;
typedef __attribute__((ext_vector_type(4))) float f32x4;

__device__ __forceinline__ u16 f2bf(float f) {
  union { float f; uint32_t u; } c; c.f = f;
  return (u16)((c.u + 0x7fffu + ((c.u >> 16) & 1u)) >> 16);
}
__device__ __forceinline__ float bf2f(u16 h) {
  union { uint32_t u; float f; } c; c.u = ((uint32_t)h) << 16;
  return c.f;
}
// global -> LDS direct DMA, 16B/lane. LDS dest is wave-uniform base + lane*16.
__device__ __forceinline__ void gload16(const void* g, void* l) {
  __builtin_amdgcn_global_load_lds(
      (__attribute__((address_space(1))) void*)g,
      (__attribute__((address_space(3))) void*)l, 16, 0, 0);
}

// ---------------- fp32 -> bf16 conversion ----------------
__global__ void cvt_w(const float* __restrict__ src, u16* __restrict__ dst, int n4) {
  int i = blockIdx.x * blockDim.x + threadIdx.x;
  if (i >= n4) return;
  float4 v = ((const float4*)src)[i];
  ushort4 o;
  o.x = f2bf(v.x); o.y = f2bf(v.y); o.z = f2bf(v.z); o.w = f2bf(v.w);
  ((ushort4*)dst)[i] = o;
}

// ---------------- split-K partial reduce: out = p0 + p1 + res (fp32) --------
__global__ __launch_bounds__(256) void down_reduce(const u16* __restrict__ p0,
                                                   const u16* __restrict__ p1,
                                                   const float* __restrict__ res,
                                                   float* __restrict__ out, int n4) {
  int i = blockIdx.x * blockDim.x + threadIdx.x;
  if (i >= n4) return;
  ushort4 a = ((const ushort4*)p0)[i];
  ushort4 b = ((const ushort4*)p1)[i];
  float4 r = ((const float4*)res)[i];
  float4 o;
  o.x = bf2f(a.x) + bf2f(b.x) + r.x;
  o.y = bf2f(a.y) + bf2f(b.y) + r.y;
  o.z = bf2f(a.z) + bf2f(b.z) + r.z;
  o.w = bf2f(a.w) + bf2f(b.w) + r.w;
  ((float4*)out)[i] = o;
}

// ---------------- RMSNorm: one block per row ----------------
__global__ __launch_bounds__(256) void rmsnorm_k(const float* __restrict__ x,
                                                 const float* __restrict__ w,
                                                 u16* __restrict__ out) {
  int row = blockIdx.x;
  int t = threadIdx.x;
  const float4* xr = (const float4*)(x + (size_t)row * H_);
  float4 a = xr[t * 2], b = xr[t * 2 + 1];
  float s = a.x*a.x + a.y*a.y + a.z*a.z + a.w*a.w
          + b.x*b.x + b.y*b.y + b.z*b.z + b.w*b.w;
  for (int m = 1; m < 64; m <<= 1) s += __shfl_xor(s, m);
  __shared__ float sm[4];
  if ((t & 63) == 0) sm[t >> 6] = s;
  __syncthreads();
  float tot = sm[0] + sm[1] + sm[2] + sm[3];
  float rs = rsqrtf(tot / (float)H_ + 1e-6f);
  const float4* wr = (const float4*)w;
  float4 w0 = wr[t * 2], w1 = wr[t * 2 + 1];
  ushort4 o0, o1;
  o0.x = f2bf(a.x * rs * w0.x); o0.y = f2bf(a.y * rs * w0.y);
  o0.z = f2bf(a.z * rs * w0.z); o0.w = f2bf(a.w * rs * w0.w);
  o1.x = f2bf(b.x * rs * w1.x); o1.y = f2bf(b.y * rs * w1.y);
  o1.z = f2bf(b.z * rs * w1.z); o1.w = f2bf(b.w * rs * w1.w);
  ushort4* orow = (ushort4*)(out + (size_t)row * H_);
  orow[t * 2] = o0; orow[t * 2 + 1] = o1;
}

// ---------------- RoPE tables ----------------
__global__ void rope_tab(float* __restrict__ cosT, float* __restrict__ sinT,
                         const int* __restrict__ offp) {
  int i = blockIdx.x * blockDim.x + threadIdx.x;  // L_*64
  int d = i & 63, l = i >> 6;
  float inv = powf(10000.0f, -(float)d / 64.0f);
  float ang = (float)(l + *offp) * inv;
  cosT[i] = cosf(ang);
  sinT[i] = sinf(ang);
}

// ---------------- RoPE apply, in-place on (B,NH,L,D) bf16 ----------------
__global__ void rope_apply(u16* __restrict__ qk, const float* __restrict__ cosT,
                           const float* __restrict__ sinT) {
  int i = blockIdx.x * blockDim.x + threadIdx.x;  // B_*NH_*L_*64
  int d = i & 63;
  size_t row = (size_t)(i >> 6);
  int l = (int)(row & (L_ - 1));
  u16* p = qk + row * D_;
  float x1 = bf2f(p[d]), x2 = bf2f(p[d + 64]);
  float c = cosT[l * 64 + d], s = sinT[l * 64 + d];
  p[d]      = f2bf(x1 * c - x2 * s);
  p[d + 64] = f2bf(x2 * c + x1 * s);
}

// ---------------- V transpose: (B,NH,L,D) -> (B,NH,D,L) ----------------
__global__ __launch_bounds__(256) void vtrans_k(const u16* __restrict__ v,
                                                u16* __restrict__ vt) {
  __shared__ u16 tile[64][65];
  int l0 = blockIdx.x * 64, d0 = blockIdx.y * 64;
  size_t base = (size_t)blockIdx.z * L_ * D_;
  int t = threadIdx.x;
  int tr = t >> 3, tc = (t & 7) * 8;
  #pragma unroll
  for (int it = 0; it < 2; ++it) {
    int r = tr + it * 32;
    const u16* src = v + base + (size_t)(l0 + r) * D_ + d0 + tc;
    ushort4 u0 = ((const ushort4*)src)[0], u1 = ((const ushort4*)src)[1];
    tile[r][tc + 0] = u0.x; tile[r][tc + 1] = u0.y;
    tile[r][tc + 2] = u0.z; tile[r][tc + 3] = u0.w;
    tile[r][tc + 4] = u1.x; tile[r][tc + 5] = u1.y;
    tile[r][tc + 6] = u1.z; tile[r][tc + 7] = u1.w;
  }
  __syncthreads();
  #pragma unroll
  for (int it = 0; it < 2; ++it) {
    int r = tr + it * 32;
    u16* dst = vt + base + (size_t)(d0 + r) * L_ + l0 + tc;
    ushort4 o0, o1;
    o0.x = tile[tc + 0][r]; o0.y = tile[tc + 1][r];
    o0.z = tile[tc + 2][r]; o0.w = tile[tc + 3][r];
    o1.x = tile[tc + 4][r]; o1.y = tile[tc + 5][r];
    o1.z = tile[tc + 6][r]; o1.w = tile[tc + 7][r];
    ((ushort4*)dst)[0] = o0; ((ushort4*)dst)[1] = o1;
  }
}

#define EPI_SILU 1
#define EPI_MUL 2
#define EPI_PART 4
#define EPI_QKV3 5
#define EPI_GLU 6

// ---------------- GEMM 256x256 8-wave quadrant-phased (r9 structure) ---------
// 512 thr = 8 waves; BK=64; LDS 128KB dbuf; vmcnt(4) counted waits; LDS XOR
// swizzle both-sides (rule #21); column-major wg->(m,n).
// FROZEN K-loop (r6/r8/r10: schedule variants null at MfmaUtil ~30-33%).
// EPI_GLU: B-rows = 128 gate rows (Bw) + 128 up rows (Bw2) for the SAME
// 128 output cols -> silu(gate)*up computed in-register, single write.
template <int EPI>
__global__ __launch_bounds__(512, 2)
void gemm256(const u16* __restrict__ A, const u16* __restrict__ Bw,
             int M, int N, int K, int nk,
             u16* __restrict__ outb, u16* __restrict__ outb2,
             const u16* __restrict__ Bw2) {
  __shared__ __attribute__((aligned(16))) u16 Asm[2][2][8192];
  __shared__ __attribute__((aligned(16))) u16 Bsm[2][2][8192];
  int tid = threadIdx.x;
  int wid = tid >> 6, lane = tid & 63;
  int r16 = lane & 15, g4 = lane >> 4;
  // bijective XCD swizzle (m204)
  int nwg = gridDim.x, bid = blockIdx.x;
  int q8 = nwg >> 3, r8 = nwg & 7, xcd = bid & 7, loc = bid >> 3;
  int wgall = (xcd < r8 ? xcd * (q8 + 1) : r8 * (q8 + 1) + (xcd - r8) * q8) + loc;
  int nwg_geo = (M >> 8) * ((EPI == EPI_GLU) ? (N >> 7) : (N >> 8));
  int ks = wgall / nwg_geo;     // split-K slice (EPI_PART)
  int wg = wgall % nwg_geo;
  int MX = M >> 8;
  int m0 = (wg % MX) * 256;     // column-major: m fastest
  int n0 = (wg / MX) * ((EPI == EPI_GLU) ? 128 : 256);
  const char* Ab = (const char*)(A + (size_t)ks * nk * 64);
  const char* Bb = (const char*)(Bw + (size_t)ks * nk * 64);
  const char* Bb2 = (const char*)Bw2;
  u16* ob = (EPI == EPI_PART && ks) ? outb2 : outb;

  f32x4 acc[2][2][4][2] = {};
  bf16x8 afr[4][2];      // A frags for current qm
  bf16x8 bfr[2][2][2];   // B frags [qn][nf][kk], both qn held

  // stage half sel of tile kt1: 0:A-h0 1:B-h0 2:B-h1 3:A-h1
  auto STAGE = [&](int kt1, int sel) {
    if (kt1 >= nk) return;
    int buf = kt1 & 1;
    int k0 = kt1 << 6;
    const char* gb; char* lb; int row0;
    if (sel == 0)      { gb = Ab; row0 = m0;       lb = (char*)&Asm[buf][0][0]; }
    else if (sel == 3) { gb = Ab; row0 = m0 + 128; lb = (char*)&Asm[buf][1][0]; }
    else if (sel == 1) { gb = Bb; row0 = n0;       lb = (char*)&Bsm[buf][0][0]; }
    else               { gb = (EPI == EPI_GLU) ? Bb2 : Bb;
                         row0 = (EPI == EPI_GLU) ? n0 : n0 + 128;
                         lb = (char*)&Bsm[buf][1][0]; }
    #pragma unroll
    for (int j = 0; j < 2; ++j) {
      int p = j * 8192 + wid * 1024 + lane * 16;
      int r = p >> 7;
      int cb = (p & 127) ^ ((r & 7) << 4);
      gload16(gb + ((size_t)(row0 + r) * K + k0) * 2 + cb,
              lb + j * 8192 + wid * 1024);
    }
  };

  // prologue: tile 0, order A0,B0,B1,A1 (8 loads in flight)
  STAGE(0, 0); STAGE(0, 1); STAGE(0, 2); STAGE(0, 3);

  const int QM[4] = {0, 0, 1, 1};
  const int QN[4] = {0, 1, 1, 0};

  for (int kt = 0; kt < nk; ++kt) {
    int cur = kt & 1;
    #pragma unroll
    for (int ph = 0; ph < 4; ++ph) {
      if (ph < 3) {
        __builtin_amdgcn_sched_barrier(0);
        asm volatile("s_waitcnt vmcnt(4)" ::: "memory");
      }
      __builtin_amdgcn_s_barrier();
      __builtin_amdgcn_sched_barrier(0);
      const int qm = QM[ph], qn = QN[ph];
      if (ph == 0 || ph == 2) {            // (re)load A frags for this qm
        const char* Ah = (const char*)&Asm[cur][qm][0];
        #pragma unroll
        for (int mf = 0; mf < 4; ++mf) {
          int R = (wid >> 2) * 64 + mf * 16 + r16;
          int sw = (R & 7) << 4;
          afr[mf][0] = *(const bf16x8*)(Ah + R * 128 + ((g4 * 16) ^ sw));
          afr[mf][1] = *(const bf16x8*)(Ah + R * 128 + ((64 + g4 * 16) ^ sw));
        }
      }
      if (ph == 0 || ph == 1) {            // load B frags for this qn
        const char* Bh = (const char*)&Bsm[cur][qn][0];
        #pragma unroll
        for (int nf = 0; nf < 2; ++nf) {
          int R = (wid & 3) * 32 + nf * 16 + r16;
          int sw = (R & 7) << 4;
          bfr[qn][nf][0] = *(const bf16x8*)(Bh + R * 128 + ((g4 * 16) ^ sw));
          bfr[qn][nf][1] = *(const bf16x8*)(Bh + R * 128 + ((64 + g4 * 16) ^ sw));
        }
      }
      STAGE(kt + 1, ph);                    // next tile, one half per phase
      __builtin_amdgcn_s_setprio(1);
      #pragma unroll
      for (int mf = 0; mf < 4; ++mf)
        #pragma unroll
        for (int nf = 0; nf < 2; ++nf)
          #pragma unroll
          for (int kk = 0; kk < 2; ++kk)
            acc[qm][qn][mf][nf] = __builtin_amdgcn_mfma_f32_16x16x32_bf16(
                afr[mf][kk], bfr[qn][nf][kk], acc[qm][qn][mf][nf], 0, 0, 0);
      __builtin_amdgcn_s_setprio(0);
    }
  }
  // epilogue
  if (EPI == EPI_GLU) {
    #pragma unroll
    for (int qm = 0; qm < 2; ++qm)
      #pragma unroll
      for (int mf = 0; mf < 4; ++mf)
        #pragma unroll
        for (int nf = 0; nf < 2; ++nf)
          #pragma unroll
          for (int rr = 0; rr < 4; ++rr) {
            int row = m0 + qm * 128 + (wid >> 2) * 64 + mf * 16 + g4 * 4 + rr;
            int col = n0 + (wid & 3) * 32 + nf * 16 + r16;
            float g = acc[qm][0][mf][nf][rr];
            float u = acc[qm][1][mf][nf][rr];
            float sg = g / (1.0f + __expf(-g));
            outb[(size_t)row * N + col] = f2bf(sg * u);
          }
    return;
  }
  #pragma unroll
  for (int qm = 0; qm < 2; ++qm)
    #pragma unroll
    for (int qn = 0; qn < 2; ++qn)
      #pragma unroll
      for (int mf = 0; mf < 4; ++mf)
        #pragma unroll
        for (int nf = 0; nf < 2; ++nf)
          #pragma unroll
          for (int rr = 0; rr < 4; ++rr) {
            int row = m0 + qm * 128 + (wid >> 2) * 64 + mf * 16 + g4 * 4 + rr;
            int col = n0 + qn * 128 + (wid & 3) * 32 + nf * 16 + r16;
            float val = acc[qm][qn][mf][nf][rr];
            if (EPI == EPI_SILU) {
              ob[(size_t)row * N + col] = f2bf(val / (1.0f + __expf(-val)));
            } else if (EPI == EPI_MUL) {
              float g = bf2f(ob[(size_t)row * N + col]);
              ob[(size_t)row * N + col] = f2bf(g * val);
            } else if (EPI == EPI_PART) {
              ob[(size_t)row * N + col] = f2bf(val);
            } else if (EPI == EPI_QKV3) {
              int which = col >> 11, within = col & 2047;
              int hh = within >> 7, d = within & 127;
              int bb = row >> 11, l = row & 2047;
              ob[(size_t)which * M_ * H_ +
                 ((((size_t)bb * NH_ + hh) * L_ + l) << 7) + d] = f2bf(val);
            }
          }
}

// ---------------- Flash attention (causal), QBLK=64, K/V dbuf (r12 best) ----
// 2-phase pipeline: STAGE(t+1,buf^1) issued BEFORE the compute of tile t;
// __syncthreads at iter end drains vmcnt AFTER ~600cyc of MFMA/softmax.
// (r13 lesson: QBLK=128 regressed ~60µs — fewer blocks + longer critical
// path beat the traffic saving. Attn is not traffic-bound; keep QBLK=64.)
// LDS 72KB -> 2 blocks/CU. XOR swizzle byte^=((row&7)<<4) both-sides.
__global__ __launch_bounds__(256)
void flash_attn(const u16* __restrict__ q, const u16* __restrict__ k,
                const u16* __restrict__ vt, u16* __restrict__ out) {
  __shared__ __attribute__((aligned(16))) u16 Kt[2][64 * 128];
  __shared__ __attribute__((aligned(16))) u16 Vt[2][128 * 64];
  __shared__ __attribute__((aligned(16))) u16 Pl[4][16 * 64];
  int tid = threadIdx.x, w = tid >> 6, lane = tid & 63;
  int r16 = lane & 15, g4 = lane >> 4;
  int b = blockIdx.z, h = blockIdx.y;
  int qt = gridDim.x - 1 - blockIdx.x;   // longest blocks dispatch first
  int q0 = qt * 64;
  size_t bh = (size_t)b * NH_ + h;
  const char* qb = (const char*)(q + bh * L_ * D_);
  const char* kb = (const char*)(k + bh * L_ * D_);
  const char* vb = (const char*)(vt + bh * D_ * L_);
  int qrow = q0 + w * 16 + r16;
  bf16x8 qf[4];
  #pragma unroll
  for (int c = 0; c < 4; ++c)
    qf[c] = *(const bf16x8*)(qb + ((size_t)qrow * 128 + c * 32 + g4 * 8) * 2);
  f32x4 oacc[8] = {};
  float mrow[4], lsum[4];
  #pragma unroll
  for (int r = 0; r < 4; ++r) { mrow[r] = -3.0e38f; lsum[r] = 0.f; }
  int myq = q0 + w * 16 + g4 * 4;
  int ntiles = qt + 1;
  int rsw = (r16 & 7) << 4;
  const float sc = 0.08838834764831845f;

  auto STAGEKV = [&](int t, int buf) {
    if (t >= ntiles) return;
    int kv0 = t * 64;
    #pragma unroll
    for (int i = 0; i < 4; ++i) {
      int uoff = i * 4096 + w * 1024;
      int lin = uoff + lane * 16;
      int krow = lin >> 8;
      int kcol = (lin & 255) ^ ((krow & 7) << 4);
      gload16(kb + (size_t)(kv0 + krow) * 256 + kcol,
              (char*)&Kt[buf][0] + uoff);
      int vrow = lin >> 7;
      int vcol = (lin & 127) ^ ((vrow & 7) << 4);
      gload16(vb + (size_t)vrow * (L_ * 2) + kv0 * 2 + vcol,
              (char*)&Vt[buf][0] + uoff);
    }
  };

  STAGEKV(0, 0);
  __syncthreads();   // implicit vmcnt(0) drain before first compute

  for (int t = 0; t < ntiles; ++t) {
    int buf = t & 1;
    int kv0 = t * 64;
    STAGEKV(t + 1, buf ^ 1);   // prefetch next tile; lands during compute
    const char* Kb = (const char*)&Kt[buf][0];
    const char* Vb = (const char*)&Vt[buf][0];
    // S = Q K^T
    f32x4 s[4] = {};
    __builtin_amdgcn_s_setprio(1);
    #pragma unroll
    for (int c = 0; c < 4; ++c) {
      #pragma unroll
      for (int n = 0; n < 4; ++n) {
        bf16x8 kf = *(const bf16x8*)(Kb + (n * 16 + r16) * 256
                                     + ((c * 64 + g4 * 16) ^ rsw));
        s[n] = __builtin_amdgcn_mfma_f32_16x16x32_bf16(qf[c], kf, s[n], 0, 0, 0);
      }
    }
    __builtin_amdgcn_s_setprio(0);
    // scale + causal mask + online softmax
    #pragma unroll
    for (int r = 0; r < 4; ++r) {
      float rm = -3.0e38f;
      #pragma unroll
      for (int n = 0; n < 4; ++n) {
        float v = s[n][r] * sc;
        int kvi = kv0 + n * 16 + r16;
        if (kvi > myq + r) v = -3.0e38f;
        s[n][r] = v;
        rm = fmaxf(rm, v);
      }
      rm = fmaxf(rm, __shfl_xor(rm, 1));
      rm = fmaxf(rm, __shfl_xor(rm, 2));
      rm = fmaxf(rm, __shfl_xor(rm, 4));
      rm = fmaxf(rm, __shfl_xor(rm, 8));
      float mnew = fmaxf(mrow[r], rm);
      float alpha = __expf(mrow[r] - mnew);
      mrow[r] = mnew;
      lsum[r] *= alpha;
      #pragma unroll
      for (int nf = 0; nf < 8; ++nf) oacc[nf][r] *= alpha;
      int prow = g4 * 4 + r;
      int psw = (prow & 7) << 3;
      #pragma unroll
      for (int n = 0; n < 4; ++n) {
        float pv = __expf(s[n][r] - mnew);
        lsum[r] += pv;
        Pl[w][prow * 64 + ((n * 16 + r16) ^ psw)] = f2bf(pv);
      }
    }
    // wave-internal LDS visibility fence (guide rule #18)
    asm volatile("s_waitcnt lgkmcnt(0)" ::: "memory");
    __builtin_amdgcn_sched_barrier(0);
    // O += P V
    __builtin_amdgcn_s_setprio(1);
    #pragma unroll
    for (int kc = 0; kc < 2; ++kc) {
      bf16x8 pf = *(const bf16x8*)((const char*)&Pl[w][0] + r16 * 128
                                   + ((kc * 64 + g4 * 16) ^ rsw));
      #pragma unroll
      for (int nf = 0; nf < 8; ++nf) {
        bf16x8 vf = *(const bf16x8*)(Vb + (nf * 16 + r16) * 128
                                     + ((kc * 64 + g4 * 16) ^ rsw));
        oacc[nf] = __builtin_amdgcn_mfma_f32_16x16x32_bf16(pf, vf, oacc[nf], 0, 0, 0);
      }
    }
    __builtin_amdgcn_s_setprio(0);
    __syncthreads();   // drains prefetch (vmcnt(0)) + publishes buf^1
  }
  #pragma unroll
  for (int r = 0; r < 4; ++r) {
    float l = lsum[r];
    l += __shfl_xor(l, 1); l += __shfl_xor(l, 2);
    l += __shfl_xor(l, 4); l += __shfl_xor(l, 8);
    float inv = 1.0f / l;
    size_t orow = ((size_t)b * L_ + (myq + r)) * H_ + h * D_;
    #pragma unroll
    for (int nf = 0; nf < 8; ++nf)
      out[orow + nf * 16 + r16] = f2bf(oacc[nf][r] * inv);
  }
}

// ---------------- host orchestration ----------------
extern "C" void kernel_launch(void* const* d_in, const int* in_sizes, int n_in,
                              void* d_out, int out_size, void* d_ws, size_t ws_size,
                              hipStream_t stream) {
  (void)in_sizes; (void)n_in; (void)out_size;
  const float* x    = (const float*)d_in[0];
  const float* ln1w = (const float*)d_in[1];
  const float* ln2w = (const float*)d_in[2];
  const float* wq   = (const float*)d_in[3];
  const float* wk   = (const float*)d_in[4];
  const float* wv   = (const float*)d_in[5];
  const float* wo   = (const float*)d_in[6];
  const float* wg   = (const float*)d_in[7];
  const float* wu   = (const float*)d_in[8];
  const float* wd   = (const float*)d_in[9];
  const int*   offp = (const int*)d_in[11];
  float* out = (float*)d_out;

  char* p = (char*)d_ws;
  auto alloc = [&](size_t bytes) {
    char* r = p;
    p += (bytes + 255) & ~(size_t)255;
    return r;
  };
  const size_t HH = (size_t)H_ * H_, IH = (size_t)I_ * H_;
  u16* wbuf = (u16*)alloc(IH * 2);                  // 32 MB, reused
  u16* h1   = (u16*)alloc((size_t)M_ * H_ * 2);     // 16 MB (h2; down partial 0)
  u16* qb   = (u16*)alloc((size_t)M_ * H_ * 2);     // 16 MB (gateb after attn)
  u16* kb   = (u16*)alloc((size_t)M_ * H_ * 2);     // 16 MB (WO partial 0)
  u16* vb   = (u16*)alloc((size_t)M_ * H_ * 2);     // 16 MB (WO partial 1)
  u16* vtb  = (u16*)alloc((size_t)M_ * H_ * 2);     // 16 MB
  u16* attn = (u16*)alloc((size_t)M_ * H_ * 2);     // 16 MB (down partial 1)
  float* x2 = (float*)alloc((size_t)M_ * H_ * 4);   // 32 MB
  float* cosT = (float*)alloc((size_t)L_ * 64 * 4);
  float* sinT = (float*)alloc((size_t)L_ * 64 * 4);
  u16* h2    = h1;   // h1 dead after QKV GEMM
  u16* gateb = qb;   // qb..vtb region dead after flash_attn / WO
  // optional second weight buffer for fused GLU (needs +32MB)
  u16* wu_b = (u16*)alloc(IH * 2);
  bool fused_glu = ((char*)wu_b + IH * 2) <= ((char*)d_ws + ws_size);

  const int nHH4 = (int)(HH / 4), nIH4 = (int)(IH / 4);

  rmsnorm_k<<<M_, 256, 0, stream>>>(x, ln1w, h1);
  rope_tab<<<(L_ * 64) / 256, 256, 0, stream>>>(cosT, sinT, offp);

  // fused QKV: wq/wk/wv stacked -> one N=6144 GEMM, scatter epilogue
  cvt_w<<<nHH4 / 256, 256, 0, stream>>>(wq, wbuf, nHH4);
  cvt_w<<<nHH4 / 256, 256, 0, stream>>>(wk, wbuf + HH, nHH4);
  cvt_w<<<nHH4 / 256, 256, 0, stream>>>(wv, wbuf + 2 * HH, nHH4);
  int nwg_qkv = (M_ / 256) * (3 * H_ / 256);   // 384
  gemm256<EPI_QKV3><<<nwg_qkv, 512, 0, stream>>>(h1, wbuf, M_, 3 * H_, H_,
                                                 H_ / 64, qb, nullptr, nullptr);

  int nrope = B_ * NH_ * L_ * 64;
  rope_apply<<<nrope / 256, 256, 0, stream>>>(qb, cosT, sinT);
  rope_apply<<<nrope / 256, 256, 0, stream>>>(qb + (size_t)M_ * H_, cosT, sinT);
  vtrans_k<<<dim3(L_ / 64, D_ / 64, B_ * NH_), 256, 0, stream>>>(
      qb + 2 * (size_t)M_ * H_, vtb);

  flash_attn<<<dim3(L_ / 64, NH_, B_), 256, 0, stream>>>(
      qb, qb + (size_t)M_ * H_, vtb, attn);

  // WO: split-K=2 on gemm256, partials kb/vb, reduce adds residual x -> x2
  cvt_w<<<nHH4 / 256, 256, 0, stream>>>(wo, wbuf, nHH4);
  int nwg_wo = 2 * (M_ / 256) * (H_ / 256);    // 256
  gemm256<EPI_PART><<<nwg_wo, 512, 0, stream>>>(attn, wbuf, M_, H_, H_,
                                                H_ / 128, kb, vb, nullptr);
  down_reduce<<<(M_ * H_ / 4) / 256, 256, 0, stream>>>(kb, vb, x, x2,
                                                       M_ * H_ / 4);
  rmsnorm_k<<<M_, 256, 0, stream>>>(x2, ln2w, h2);

  if (fused_glu) {
    // fused gate+up: one pass, silu(g)*u in-register (no RMW traffic)
    cvt_w<<<nIH4 / 256, 256, 0, stream>>>(wg, wbuf, nIH4);
    cvt_w<<<nIH4 / 256, 256, 0, stream>>>(wu, wu_b, nIH4);
    int nwg_glu = (M_ / 256) * (I_ / 128);     // 16*64 = 1024
    gemm256<EPI_GLU><<<nwg_glu, 512, 0, stream>>>(h2, wbuf, M_, I_, H_,
                                                  H_ / 64, gateb, nullptr, wu_b);
  } else {
    int nwg256 = (M_ / 256) * (I_ / 256);
    cvt_w<<<nIH4 / 256, 256, 0, stream>>>(wg, wbuf, nIH4);
    gemm256<EPI_SILU><<<nwg256, 512, 0, stream>>>(h2, wbuf, M_, I_, H_,
                                                  H_ / 64, gateb, nullptr, nullptr);
    cvt_w<<<nIH4 / 256, 256, 0, stream>>>(wu, wbuf, nIH4);
    gemm256<EPI_MUL><<<nwg256, 512, 0, stream>>>(h2, wbuf, M_, I_, H_,
                                                 H_ / 64, gateb, nullptr, nullptr);
  }

  // down-proj: split-K=2, partials h1/attn, reduce adds residual x2 -> out
  cvt_w<<<nIH4 / 256, 256, 0, stream>>>(wd, wbuf, nIH4);
  int nwg_dn = 2 * (M_ / 256) * (H_ / 256);    // 256
  gemm256<EPI_PART><<<nwg_dn, 512, 0, stream>>>(gateb, wbuf, M_, H_, I_,
                                                I_ / 128, h1, attn, nullptr);
  down_reduce<<<(M_ * H_ / 4) / 256, 256, 0, stream>>>(h1, attn, x2, out,
                                                       M_ * H_ / 4);
}